// Round 2
// baseline (6399.171 us; speedup 1.0000x reference)
//
#include <hip/hip_runtime.h>

#define D 128
#define HALF 64
constexpr int NPB = 8;

// ---------------- init: gather + mean + concat + [320x128] proj ----------------
__global__ __launch_bounds__(256) void init_nodes_kernel(
    const int* __restrict__ feat_ids,      // [n,10]
    const int* __restrict__ text_ids,      // [n,3,8]
    const float* __restrict__ feat_emb,    // [*,128]
    const float* __restrict__ word_emb,    // [30000,64]
    const float* __restrict__ projW,       // [320,128] row-major
    const float* __restrict__ projb,       // [128]
    const float* __restrict__ id_emb,      // [n,128]
    float* __restrict__ xout,              // write rows (out_base+g)
    int n_nodes, int out_base)
{
    __shared__ float in_s[NPB][320];
    __shared__ int fid_s[NPB][10];
    __shared__ int tid_s[NPB][24];
    const int base = blockIdx.x * NPB;
    const int t = threadIdx.x;

    for (int i = t; i < NPB * 10; i += 256) {
        int node = i / 10, j = i % 10, g = base + node;
        if (g < n_nodes) fid_s[node][j] = feat_ids[(size_t)g * 10 + j];
    }
    for (int i = t; i < NPB * 24; i += 256) {
        int node = i / 24, j = i % 24, g = base + node;
        if (g < n_nodes) tid_s[node][j] = text_ids[(size_t)g * 24 + j];
    }
    __syncthreads();

    // feat mean -> in_s[node][0..127]
    for (int i = t; i < NPB * 128; i += 256) {
        int node = i >> 7, d = i & 127, g = base + node;
        if (g >= n_nodes) continue;
        float acc = 0.f;
        #pragma unroll
        for (int j = 0; j < 10; ++j) acc += feat_emb[(size_t)fid_s[node][j] * D + d];
        in_s[node][d] = acc * 0.1f;
    }
    // text field means -> in_s[node][128..319]
    for (int i = t; i < NPB * 192; i += 256) {
        int node = i / 192, tt = i % 192, g = base + node;
        if (g >= n_nodes) continue;
        int f = tt >> 6, d2 = tt & 63;
        float acc = 0.f;
        #pragma unroll
        for (int w = 0; w < 8; ++w) acc += word_emb[(size_t)tid_s[node][f * 8 + w] * HALF + d2];
        in_s[node][128 + tt] = acc * 0.125f;
    }
    __syncthreads();

    const int d = t & 127, half = t >> 7;
    float acc[4] = {0.f, 0.f, 0.f, 0.f};
    for (int k = 0; k < 320; ++k) {
        float w = projW[k * D + d];
        #pragma unroll
        for (int nn = 0; nn < 4; ++nn) acc[nn] += in_s[half * 4 + nn][k] * w;
    }
    const float b = projb[d];
    #pragma unroll
    for (int nn = 0; nn < 4; ++nn) {
        int node = half * 4 + nn, g = base + node;
        if (g < n_nodes)
            xout[(size_t)(out_base + g) * D + d] = acc[nn] + b + id_emb[(size_t)g * D + d];
    }
}

// ---------------- degree ----------------
__global__ __launch_bounds__(256) void deg_kernel(
    const int* __restrict__ dst, int E, float* __restrict__ deg)
{
    int e = blockIdx.x * 256 + threadIdx.x;
    if (e < E) atomicAdd(&deg[dst[e]], 1.0f);
}

// ---------------- edge scatter-add: agg[dst] += x[src] ----------------
__global__ __launch_bounds__(256) void scatter_kernel(
    const int* __restrict__ src, const int* __restrict__ dst, long total,
    const float* __restrict__ x, float* __restrict__ agg)
{
    long idx = (long)blockIdx.x * 256 + threadIdx.x;
    if (idx >= total) return;
    int e = (int)(idx >> 5), q = (int)(idx & 31);
    int s = src[e], dd = dst[e];
    const float4 v = *(const float4*)&x[(size_t)s * D + q * 4];
    float* p = &agg[(size_t)dd * D + q * 4];
    atomicAdd(p + 0, v.x);
    atomicAdd(p + 1, v.y);
    atomicAdd(p + 2, v.z);
    atomicAdd(p + 3, v.w);
}

// ---------------- SAGE layer: t=relu(agg/deg @ vW + vb); x=concat(x,t)@wW+wb ----------------
__global__ __launch_bounds__(256) void sage_kernel(
    const float* __restrict__ x, const float* __restrict__ aggr,
    const float* __restrict__ deg,
    const float* __restrict__ vW, const float* __restrict__ vb,  // [128,128],[128]
    const float* __restrict__ wW, const float* __restrict__ wb,  // [256,128],[128]
    float* __restrict__ xout, int n_nodes, int relu_out)
{
    __shared__ float x_s[NPB][D];
    __shared__ float a_s[NPB][D];
    __shared__ float t_s[NPB][D];
    const int base = blockIdx.x * NPB;
    const int t = threadIdx.x;

    for (int i = t; i < NPB * D; i += 256) {
        int node = i >> 7, d = i & 127, g = base + node;
        if (g >= n_nodes) continue;
        x_s[node][d] = x[(size_t)g * D + d];
        float inv = 1.0f / fmaxf(deg[g], 1.0f);
        a_s[node][d] = aggr[(size_t)g * D + d] * inv;
    }
    __syncthreads();

    const int d = t & 127, half = t >> 7;
    {
        float acc[4] = {0.f, 0.f, 0.f, 0.f};
        for (int k = 0; k < D; ++k) {
            float w = vW[k * D + d];
            #pragma unroll
            for (int nn = 0; nn < 4; ++nn) acc[nn] += a_s[half * 4 + nn][k] * w;
        }
        float b = vb[d];
        #pragma unroll
        for (int nn = 0; nn < 4; ++nn) t_s[half * 4 + nn][d] = fmaxf(acc[nn] + b, 0.f);
    }
    __syncthreads();
    {
        float acc[4] = {0.f, 0.f, 0.f, 0.f};
        for (int k = 0; k < D; ++k) {
            float w = wW[k * D + d];
            #pragma unroll
            for (int nn = 0; nn < 4; ++nn) acc[nn] += x_s[half * 4 + nn][k] * w;
        }
        for (int k = 0; k < D; ++k) {
            float w = wW[(128 + k) * D + d];
            #pragma unroll
            for (int nn = 0; nn < 4; ++nn) acc[nn] += t_s[half * 4 + nn][k] * w;
        }
        float b = wb[d];
        #pragma unroll
        for (int nn = 0; nn < 4; ++nn) {
            int g = base + half * 4 + nn;
            if (g < n_nodes) {
                float o = acc[nn] + b;
                if (relu_out) o = fmaxf(o, 0.f);
                xout[(size_t)g * D + d] = o;
            }
        }
    }
}

extern "C" void kernel_launch(void* const* d_in, const int* in_sizes, int n_in,
                              void* d_out, int out_size, void* d_ws, size_t ws_size,
                              hipStream_t stream)
{
    const int* edge_index      = (const int*)d_in[0];
    const int* user_features   = (const int*)d_in[1];
    const int* item_features   = (const int*)d_in[2];
    const int* user_text       = (const int*)d_in[3];
    const int* item_text       = (const int*)d_in[4];
    const float* user_id_emb   = (const float*)d_in[5];
    const float* item_id_emb   = (const float*)d_in[6];
    const float* user_feat_emb = (const float*)d_in[7];
    const float* item_feat_emb = (const float*)d_in[8];
    const float* word_emb      = (const float*)d_in[9];
    const float* user_projW    = (const float*)d_in[10];
    const float* user_projb    = (const float*)d_in[11];
    const float* item_projW    = (const float*)d_in[12];
    const float* item_projb    = (const float*)d_in[13];
    const float* w0W = (const float*)d_in[14];
    const float* w0b = (const float*)d_in[15];
    const float* w1W = (const float*)d_in[16];
    const float* w1b = (const float*)d_in[17];
    const float* v0W = (const float*)d_in[18];
    const float* v0b = (const float*)d_in[19];
    const float* v1W = (const float*)d_in[20];
    const float* v1b = (const float*)d_in[21];

    const int E  = in_sizes[0] / 2;
    const int NU = in_sizes[5] / D;
    const int NI = in_sizes[6] / D;
    const int N  = NU + NI;

    float* x   = (float*)d_out;              // x lives in d_out; updated in place
    float* agg = (float*)d_ws;               // [N,128]
    float* deg = agg + (size_t)N * D;        // [N]

    hipMemsetAsync(agg, 0, (size_t)(N * D + N) * sizeof(float), stream);

    const int* src = edge_index;
    const int* dst = edge_index + E;
    dim3 blk(256);

    init_nodes_kernel<<<(NU + NPB - 1) / NPB, blk, 0, stream>>>(
        user_features, user_text, user_feat_emb, word_emb,
        user_projW, user_projb, user_id_emb, x, NU, 0);
    init_nodes_kernel<<<(NI + NPB - 1) / NPB, blk, 0, stream>>>(
        item_features, item_text, item_feat_emb, word_emb,
        item_projW, item_projb, item_id_emb, x, NI, NU);

    deg_kernel<<<(E + 255) / 256, blk, 0, stream>>>(dst, E, deg);

    const long total = (long)E * 32;
    const int sblocks = (int)((total + 255) / 256);

    scatter_kernel<<<sblocks, blk, 0, stream>>>(src, dst, total, x, agg);
    sage_kernel<<<(N + NPB - 1) / NPB, blk, 0, stream>>>(
        x, agg, deg, v0W, v0b, w0W, w0b, x, N, 1);

    hipMemsetAsync(agg, 0, (size_t)N * D * sizeof(float), stream);

    scatter_kernel<<<sblocks, blk, 0, stream>>>(src, dst, total, x, agg);
    sage_kernel<<<(N + NPB - 1) / NPB, blk, 0, stream>>>(
        x, agg, deg, v1W, v1b, w1W, w1b, x, N, 0);
}

// Round 3
// 1688.874 us; speedup vs baseline: 3.7890x; 3.7890x over previous
//
#include <hip/hip_runtime.h>

#define D 128
#define HALF 64
constexpr int NPB = 8;

// ---------------- init: gather + mean + concat + [320x128] proj ----------------
__global__ __launch_bounds__(256) void init_nodes_kernel(
    const int* __restrict__ feat_ids,      // [n,10]
    const int* __restrict__ text_ids,      // [n,3,8]
    const float* __restrict__ feat_emb,    // [*,128]
    const float* __restrict__ word_emb,    // [30000,64]
    const float* __restrict__ projW,       // [320,128] row-major
    const float* __restrict__ projb,       // [128]
    const float* __restrict__ id_emb,      // [n,128]
    float* __restrict__ xout,              // write rows (out_base+g)
    int n_nodes, int out_base)
{
    __shared__ float in_s[NPB][320];
    __shared__ int fid_s[NPB][10];
    __shared__ int tid_s[NPB][24];
    const int base = blockIdx.x * NPB;
    const int t = threadIdx.x;

    for (int i = t; i < NPB * 10; i += 256) {
        int node = i / 10, j = i % 10, g = base + node;
        if (g < n_nodes) fid_s[node][j] = feat_ids[(size_t)g * 10 + j];
    }
    for (int i = t; i < NPB * 24; i += 256) {
        int node = i / 24, j = i % 24, g = base + node;
        if (g < n_nodes) tid_s[node][j] = text_ids[(size_t)g * 24 + j];
    }
    __syncthreads();

    for (int i = t; i < NPB * 128; i += 256) {
        int node = i >> 7, d = i & 127, g = base + node;
        if (g >= n_nodes) continue;
        float acc = 0.f;
        #pragma unroll
        for (int j = 0; j < 10; ++j) acc += feat_emb[(size_t)fid_s[node][j] * D + d];
        in_s[node][d] = acc * 0.1f;
    }
    for (int i = t; i < NPB * 192; i += 256) {
        int node = i / 192, tt = i % 192, g = base + node;
        if (g >= n_nodes) continue;
        int f = tt >> 6, d2 = tt & 63;
        float acc = 0.f;
        #pragma unroll
        for (int w = 0; w < 8; ++w) acc += word_emb[(size_t)tid_s[node][f * 8 + w] * HALF + d2];
        in_s[node][128 + tt] = acc * 0.125f;
    }
    __syncthreads();

    const int d = t & 127, half = t >> 7;
    float acc[4] = {0.f, 0.f, 0.f, 0.f};
    for (int k = 0; k < 320; ++k) {
        float w = projW[k * D + d];
        #pragma unroll
        for (int nn = 0; nn < 4; ++nn) acc[nn] += in_s[half * 4 + nn][k] * w;
    }
    const float b = projb[d];
    #pragma unroll
    for (int nn = 0; nn < 4; ++nn) {
        int node = half * 4 + nn, g = base + node;
        if (g < n_nodes)
            xout[(size_t)(out_base + g) * D + d] = acc[nn] + b + id_emb[(size_t)g * D + d];
    }
}

// ---------------- CSR build ----------------
__global__ __launch_bounds__(256) void hist_kernel(
    const int* __restrict__ dst, int E, int* __restrict__ deg)
{
    int e = blockIdx.x * 256 + threadIdx.x;
    if (e < E) atomicAdd(&deg[dst[e]], 1);
}

// per-block (1024 elems) exclusive scan; writes local exclusive into out_ex, block total into bsums
__global__ __launch_bounds__(256) void scan1_kernel(
    const int* __restrict__ deg, int n, int* __restrict__ out_ex, int* __restrict__ bsums)
{
    __shared__ int s[256];
    const int t = threadIdx.x;
    const int base = blockIdx.x * 1024 + t * 4;
    int v0 = 0, v1 = 0, v2 = 0, v3 = 0;
    if (base + 0 < n) v0 = deg[base + 0];
    if (base + 1 < n) v1 = deg[base + 1];
    if (base + 2 < n) v2 = deg[base + 2];
    if (base + 3 < n) v3 = deg[base + 3];
    int sum = v0 + v1 + v2 + v3;
    s[t] = sum;
    __syncthreads();
    for (int off = 1; off < 256; off <<= 1) {
        int tmp = (t >= off) ? s[t - off] : 0;
        __syncthreads();
        s[t] += tmp;
        __syncthreads();
    }
    int ex = s[t] - sum;  // exclusive prefix of this thread's chunk
    if (t == 255) bsums[blockIdx.x] = s[255];
    if (base + 0 < n) out_ex[base + 0] = ex;
    if (base + 1 < n) out_ex[base + 1] = ex + v0;
    if (base + 2 < n) out_ex[base + 2] = ex + v0 + v1;
    if (base + 3 < n) out_ex[base + 3] = ex + v0 + v1 + v2;
}

// single-block exclusive scan of block sums (nb <= 256)
__global__ __launch_bounds__(256) void scan2_kernel(int* __restrict__ bsums, int nb)
{
    __shared__ int s[256];
    const int t = threadIdx.x;
    int v = (t < nb) ? bsums[t] : 0;
    s[t] = v;
    __syncthreads();
    for (int off = 1; off < 256; off <<= 1) {
        int tmp = (t >= off) ? s[t - off] : 0;
        __syncthreads();
        s[t] += tmp;
        __syncthreads();
    }
    if (t < nb) bsums[t] = s[t] - v;  // exclusive
}

__global__ __launch_bounds__(256) void scan3_kernel(
    int* __restrict__ row_ptr, const int* __restrict__ bsums, int n, int E)
{
    const int add = bsums[blockIdx.x];
    const int base = blockIdx.x * 1024 + threadIdx.x * 4;
    #pragma unroll
    for (int j = 0; j < 4; ++j)
        if (base + j < n) row_ptr[base + j] += add;
    if (blockIdx.x == 0 && threadIdx.x == 0) row_ptr[n] = E;
}

__global__ __launch_bounds__(256) void fill_kernel(
    const int* __restrict__ src, const int* __restrict__ dst, int E,
    const int* __restrict__ row_ptr, int* __restrict__ cursor, int* __restrict__ ebuf)
{
    int e = blockIdx.x * 256 + threadIdx.x;
    if (e < E) {
        int d = dst[e];
        int slot = atomicAdd(&cursor[d], 1);
        ebuf[row_ptr[d] + slot] = src[e];
    }
}

// ---------------- gather aggregate: agg[g] = mean_{e in CSR(g)} x[src_e] ----------------
// one wave per node; lane l covers dims [2l, 2l+1]
__global__ __launch_bounds__(256) void aggregate_kernel(
    const int* __restrict__ row_ptr, const int* __restrict__ ebuf,
    const float* __restrict__ x, float* __restrict__ agg, int n_nodes)
{
    const int wave = threadIdx.x >> 6;
    const int lane = threadIdx.x & 63;
    const int g = blockIdx.x * 4 + wave;
    if (g >= n_nodes) return;
    const int s0 = row_ptr[g], s1 = row_ptr[g + 1];
    float2 acc = make_float2(0.f, 0.f);
    for (int e = s0; e < s1; ++e) {
        int s = ebuf[e];
        float2 v = *(const float2*)&x[(size_t)s * D + lane * 2];
        acc.x += v.x;
        acc.y += v.y;
    }
    const float inv = 1.0f / fmaxf((float)(s1 - s0), 1.0f);
    ((float2*)&agg[(size_t)g * D])[lane] = make_float2(acc.x * inv, acc.y * inv);
}

// ---------------- SAGE layer: t=relu(aggm @ vW + vb); x=concat(x,t)@wW+wb ----------------
__global__ __launch_bounds__(256) void sage_kernel(
    const float* __restrict__ x, const float* __restrict__ aggm,
    const float* __restrict__ vW, const float* __restrict__ vb,  // [128,128],[128]
    const float* __restrict__ wW, const float* __restrict__ wb,  // [256,128],[128]
    float* __restrict__ xout, int n_nodes, int relu_out)
{
    __shared__ float x_s[NPB][D];
    __shared__ float a_s[NPB][D];
    __shared__ float t_s[NPB][D];
    const int base = blockIdx.x * NPB;
    const int t = threadIdx.x;

    for (int i = t; i < NPB * D; i += 256) {
        int node = i >> 7, d = i & 127, g = base + node;
        if (g >= n_nodes) continue;
        x_s[node][d] = x[(size_t)g * D + d];
        a_s[node][d] = aggm[(size_t)g * D + d];
    }
    __syncthreads();

    const int d = t & 127, half = t >> 7;
    {
        float acc[4] = {0.f, 0.f, 0.f, 0.f};
        for (int k = 0; k < D; ++k) {
            float w = vW[k * D + d];
            #pragma unroll
            for (int nn = 0; nn < 4; ++nn) acc[nn] += a_s[half * 4 + nn][k] * w;
        }
        float b = vb[d];
        #pragma unroll
        for (int nn = 0; nn < 4; ++nn) t_s[half * 4 + nn][d] = fmaxf(acc[nn] + b, 0.f);
    }
    __syncthreads();
    {
        float acc[4] = {0.f, 0.f, 0.f, 0.f};
        for (int k = 0; k < D; ++k) {
            float w = wW[k * D + d];
            #pragma unroll
            for (int nn = 0; nn < 4; ++nn) acc[nn] += x_s[half * 4 + nn][k] * w;
        }
        for (int k = 0; k < D; ++k) {
            float w = wW[(128 + k) * D + d];
            #pragma unroll
            for (int nn = 0; nn < 4; ++nn) acc[nn] += t_s[half * 4 + nn][k] * w;
        }
        float b = wb[d];
        #pragma unroll
        for (int nn = 0; nn < 4; ++nn) {
            int g = base + half * 4 + nn;
            if (g < n_nodes) {
                float o = acc[nn] + b;
                if (relu_out) o = fmaxf(o, 0.f);
                xout[(size_t)g * D + d] = o;
            }
        }
    }
}

extern "C" void kernel_launch(void* const* d_in, const int* in_sizes, int n_in,
                              void* d_out, int out_size, void* d_ws, size_t ws_size,
                              hipStream_t stream)
{
    const int* edge_index      = (const int*)d_in[0];
    const int* user_features   = (const int*)d_in[1];
    const int* item_features   = (const int*)d_in[2];
    const int* user_text       = (const int*)d_in[3];
    const int* item_text       = (const int*)d_in[4];
    const float* user_id_emb   = (const float*)d_in[5];
    const float* item_id_emb   = (const float*)d_in[6];
    const float* user_feat_emb = (const float*)d_in[7];
    const float* item_feat_emb = (const float*)d_in[8];
    const float* word_emb      = (const float*)d_in[9];
    const float* user_projW    = (const float*)d_in[10];
    const float* user_projb    = (const float*)d_in[11];
    const float* item_projW    = (const float*)d_in[12];
    const float* item_projb    = (const float*)d_in[13];
    const float* w0W = (const float*)d_in[14];
    const float* w0b = (const float*)d_in[15];
    const float* w1W = (const float*)d_in[16];
    const float* w1b = (const float*)d_in[17];
    const float* v0W = (const float*)d_in[18];
    const float* v0b = (const float*)d_in[19];
    const float* v1W = (const float*)d_in[20];
    const float* v1b = (const float*)d_in[21];

    const int E  = in_sizes[0] / 2;
    const int NU = in_sizes[5] / D;
    const int NI = in_sizes[6] / D;
    const int N  = NU + NI;
    const int NB = (N + 1023) / 1024;   // scan blocks (147 for N=150000, <=256)

    float* x = (float*)d_out;  // x lives in d_out; updated in place (sage only touches own rows)

    // workspace layout
    float* agg    = (float*)d_ws;                 // [N,128] floats
    int* row_ptr  = (int*)(agg + (size_t)N * D);  // [N+1]
    int* deg_i    = row_ptr + (N + 1);            // [N]
    int* cursor   = deg_i + N;                    // [N]
    int* bsums    = cursor + N;                   // [256]
    int* ebuf     = bsums + 256;                  // [E]

    hipMemsetAsync(deg_i, 0, (size_t)(2 * N) * sizeof(int), stream);  // deg_i + cursor

    const int* src = edge_index;
    const int* dst = edge_index + E;
    dim3 blk(256);

    init_nodes_kernel<<<(NU + NPB - 1) / NPB, blk, 0, stream>>>(
        user_features, user_text, user_feat_emb, word_emb,
        user_projW, user_projb, user_id_emb, x, NU, 0);
    init_nodes_kernel<<<(NI + NPB - 1) / NPB, blk, 0, stream>>>(
        item_features, item_text, item_feat_emb, word_emb,
        item_projW, item_projb, item_id_emb, x, NI, NU);

    // CSR build
    hist_kernel<<<(E + 255) / 256, blk, 0, stream>>>(dst, E, deg_i);
    scan1_kernel<<<NB, blk, 0, stream>>>(deg_i, N, row_ptr, bsums);
    scan2_kernel<<<1, blk, 0, stream>>>(bsums, NB);
    scan3_kernel<<<NB, blk, 0, stream>>>(row_ptr, bsums, N, E);
    fill_kernel<<<(E + 255) / 256, blk, 0, stream>>>(src, dst, E, row_ptr, cursor, ebuf);

    // layer 0
    aggregate_kernel<<<(N + 3) / 4, blk, 0, stream>>>(row_ptr, ebuf, x, agg, N);
    sage_kernel<<<(N + NPB - 1) / NPB, blk, 0, stream>>>(
        x, agg, v0W, v0b, w0W, w0b, x, N, 1);

    // layer 1
    aggregate_kernel<<<(N + 3) / 4, blk, 0, stream>>>(row_ptr, ebuf, x, agg, N);
    sage_kernel<<<(N + NPB - 1) / NPB, blk, 0, stream>>>(
        x, agg, v1W, v1b, w1W, w1b, x, N, 0);
}

// Round 6
// 1314.586 us; speedup vs baseline: 4.8678x; 1.2847x over previous
//
#include <hip/hip_runtime.h>

#define D 128
#define HALF 64
constexpr int NPB = 8;

typedef __attribute__((ext_vector_type(8))) short short8;
typedef __attribute__((ext_vector_type(4))) float f32x4;
typedef unsigned short u16;
typedef unsigned int u32;

__device__ __forceinline__ u16 f2b(float f) {
    u32 u = __builtin_bit_cast(u32, f);
    u32 r = (u + 0x7fffu + ((u >> 16) & 1u)) >> 16;
    return (u16)r;
}
__device__ __forceinline__ float b2f_lo(u32 v) { return __builtin_bit_cast(float, v << 16); }
__device__ __forceinline__ float b2f_hi(u32 v) { return __builtin_bit_cast(float, v & 0xffff0000u); }

// ---------------- weight transpose+convert: out[n][k] = (bf16)in[k][n] ----------------
__global__ __launch_bounds__(256) void transpose_bf16_kernel(
    const float* __restrict__ in, u16* __restrict__ out, int K, int N)
{
    int idx = blockIdx.x * 256 + threadIdx.x;
    if (idx >= K * N) return;
    int k = idx / N, n = idx % N;
    out[(size_t)n * K + k] = f2b(in[idx]);
}

// ---------------- init: gather + mean + concat + [320x128] proj -> bf16 xb ----------------
__global__ __launch_bounds__(256) void init_nodes_kernel(
    const int* __restrict__ feat_ids,      // [n,10]
    const int* __restrict__ text_ids,      // [n,3,8]
    const float* __restrict__ feat_emb,    // [*,128]
    const float* __restrict__ word_emb,    // [30000,64]
    const float* __restrict__ projW,       // [320,128] row-major
    const float* __restrict__ projb,       // [128]
    const float* __restrict__ id_emb,      // [n,128]
    u16* __restrict__ xb,                  // write rows (out_base+g), bf16
    int n_nodes, int out_base)
{
    __shared__ float in_s[NPB][320];
    __shared__ int fid_s[NPB][10];
    __shared__ int tid_s[NPB][24];
    const int base = blockIdx.x * NPB;
    const int t = threadIdx.x;

    for (int i = t; i < NPB * 10; i += 256) {
        int node = i / 10, j = i % 10, g = base + node;
        if (g < n_nodes) fid_s[node][j] = feat_ids[(size_t)g * 10 + j];
    }
    for (int i = t; i < NPB * 24; i += 256) {
        int node = i / 24, j = i % 24, g = base + node;
        if (g < n_nodes) tid_s[node][j] = text_ids[(size_t)g * 24 + j];
    }
    __syncthreads();

    for (int i = t; i < NPB * 128; i += 256) {
        int node = i >> 7, d = i & 127, g = base + node;
        if (g >= n_nodes) continue;
        float acc = 0.f;
        #pragma unroll
        for (int j = 0; j < 10; ++j) acc += feat_emb[(size_t)fid_s[node][j] * D + d];
        in_s[node][d] = acc * 0.1f;
    }
    for (int i = t; i < NPB * 192; i += 256) {
        int node = i / 192, tt = i % 192, g = base + node;
        if (g >= n_nodes) continue;
        int f = tt >> 6, d2 = tt & 63;
        float acc = 0.f;
        #pragma unroll
        for (int w = 0; w < 8; ++w) acc += word_emb[(size_t)tid_s[node][f * 8 + w] * HALF + d2];
        in_s[node][128 + tt] = acc * 0.125f;
    }
    __syncthreads();

    const int d = t & 127, half = t >> 7;
    float acc[4] = {0.f, 0.f, 0.f, 0.f};
    for (int k = 0; k < 320; ++k) {
        float w = projW[k * D + d];
        #pragma unroll
        for (int nn = 0; nn < 4; ++nn) acc[nn] += in_s[half * 4 + nn][k] * w;
    }
    const float b = projb[d];
    #pragma unroll
    for (int nn = 0; nn < 4; ++nn) {
        int node = half * 4 + nn, g = base + node;
        if (g < n_nodes)
            xb[(size_t)(out_base + g) * D + d] = f2b(acc[nn] + b + id_emb[(size_t)g * D + d]);
    }
}

// ---------------- CSR build ----------------
__global__ __launch_bounds__(256) void hist_kernel(
    const int* __restrict__ dst, int E, int* __restrict__ deg)
{
    int e = blockIdx.x * 256 + threadIdx.x;
    if (e < E) atomicAdd(&deg[dst[e]], 1);
}

__global__ __launch_bounds__(256) void scan1_kernel(
    const int* __restrict__ deg, int n, int* __restrict__ out_ex, int* __restrict__ bsums)
{
    __shared__ int s[256];
    const int t = threadIdx.x;
    const int base = blockIdx.x * 1024 + t * 4;
    int v0 = 0, v1 = 0, v2 = 0, v3 = 0;
    if (base + 0 < n) v0 = deg[base + 0];
    if (base + 1 < n) v1 = deg[base + 1];
    if (base + 2 < n) v2 = deg[base + 2];
    if (base + 3 < n) v3 = deg[base + 3];
    int sum = v0 + v1 + v2 + v3;
    s[t] = sum;
    __syncthreads();
    for (int off = 1; off < 256; off <<= 1) {
        int tmp = (t >= off) ? s[t - off] : 0;
        __syncthreads();
        s[t] += tmp;
        __syncthreads();
    }
    int ex = s[t] - sum;
    if (t == 255) bsums[blockIdx.x] = s[255];
    if (base + 0 < n) out_ex[base + 0] = ex;
    if (base + 1 < n) out_ex[base + 1] = ex + v0;
    if (base + 2 < n) out_ex[base + 2] = ex + v0 + v1;
    if (base + 3 < n) out_ex[base + 3] = ex + v0 + v1 + v2;
}

__global__ __launch_bounds__(256) void scan2_kernel(int* __restrict__ bsums, int nb)
{
    __shared__ int s[256];
    const int t = threadIdx.x;
    int v = (t < nb) ? bsums[t] : 0;
    s[t] = v;
    __syncthreads();
    for (int off = 1; off < 256; off <<= 1) {
        int tmp = (t >= off) ? s[t - off] : 0;
        __syncthreads();
        s[t] += tmp;
        __syncthreads();
    }
    if (t < nb) bsums[t] = s[t] - v;
}

__global__ __launch_bounds__(256) void scan3_kernel(
    int* __restrict__ row_ptr, const int* __restrict__ bsums, int n, int E)
{
    const int add = bsums[blockIdx.x];
    const int base = blockIdx.x * 1024 + threadIdx.x * 4;
    #pragma unroll
    for (int j = 0; j < 4; ++j)
        if (base + j < n) row_ptr[base + j] += add;
    if (blockIdx.x == 0 && threadIdx.x == 0) row_ptr[n] = E;
}

__global__ __launch_bounds__(256) void fill_kernel(
    const int* __restrict__ src, const int* __restrict__ dst, int E,
    const int* __restrict__ row_ptr, int* __restrict__ cursor, int* __restrict__ ebuf)
{
    int e = blockIdx.x * 256 + threadIdx.x;
    if (e < E) {
        int d = dst[e];
        int slot = atomicAdd(&cursor[d], 1);
        ebuf[row_ptr[d] + slot] = src[e];
    }
}

// ---------------- gather aggregate (bf16): aggm[g] = mean x[src] ----------------
// one wave per node; lane l covers dims [2l, 2l+1] (one u32 = 2 bf16)
__global__ __launch_bounds__(256) void aggregate_kernel(
    const int* __restrict__ row_ptr, const int* __restrict__ ebuf,
    const u16* __restrict__ xb, u16* __restrict__ aggm, int n_nodes)
{
    const int wave = threadIdx.x >> 6;
    const int lane = threadIdx.x & 63;
    const int g = blockIdx.x * 4 + wave;
    if (g >= n_nodes) return;
    const int s0 = row_ptr[g], s1 = row_ptr[g + 1];
    float ax = 0.f, ay = 0.f;
    for (int e = s0; e < s1; ++e) {
        int s = ebuf[e];
        u32 v = *(const u32*)&xb[(size_t)s * D + lane * 2];
        ax += b2f_lo(v);
        ay += b2f_hi(v);
    }
    const float inv = 1.0f / fmaxf((float)(s1 - s0), 1.0f);
    u32 o = (u32)f2b(ax * inv) | ((u32)f2b(ay * inv) << 16);
    *(u32*)&aggm[(size_t)g * D + lane * 2] = o;
}

// ---------------- SAGE layer via MFMA (transposed GEMMs) ----------------
// t^T = relu(Vt @ aggm^T + vb);  out^T = Wt @ concat(xb,t)^T + wb
// A-frag: lane holds (weight-T) row l&15, k=(l>>4)*8..+7 (16B contiguous)
// B-frag: lane holds node row l&15, same k slice (16B contiguous, from global)
// C-frag: col = l&15 (node), row = (l>>4)*4+r (out dim)  [m89-verified]
#define MFMA __builtin_amdgcn_mfma_f32_16x16x32_bf16
__global__ __launch_bounds__(256) void sage_mfma_kernel(
    const u16* __restrict__ xb, const u16* __restrict__ aggm,
    const u16* __restrict__ Vt,  const float* __restrict__ vb,   // Vt [128][128]
    const u16* __restrict__ Wt,  const float* __restrict__ wb,   // Wt [128][256]
    u16* __restrict__ xb_out,    // layer0: write bf16 in place (else null)
    float* __restrict__ f_out,   // layer1: write fp32 d_out (else null)
    int n_nodes)
{
    __shared__ u16 t_lds[128][136];   // padded: 272 B row -> 2-way banks max, 16B-aligned
    const int wid  = threadIdx.x >> 6;
    const int lane = threadIdx.x & 63;
    const int row16 = lane & 15;      // node-within-group / weight row
    const int kq    = lane >> 4;      // k-quarter
    const int nb = blockIdx.x * 128 + wid * 32;

    #pragma unroll
    for (int g = 0; g < 2; ++g) {
        const int node = nb + g * 16 + row16;
        const int nclamp = node < n_nodes ? node : n_nodes - 1;
        const int tl_row = wid * 32 + g * 16 + row16;

        // ---- t^T = relu(Vt @ agg^T + vb), K=128 ----
        short8 Ba[4];
        #pragma unroll
        for (int kk = 0; kk < 4; ++kk)
            Ba[kk] = *(const short8*)&aggm[(size_t)nclamp * D + kk * 32 + kq * 8];
        #pragma unroll
        for (int fp = 0; fp < 4; ++fp) {
            const int fn0 = fp * 2, fn1 = fp * 2 + 1;
            f32x4 c0 = {0.f, 0.f, 0.f, 0.f}, c1 = {0.f, 0.f, 0.f, 0.f};
            #pragma unroll
            for (int kk = 0; kk < 4; ++kk) {
                short8 A0 = *(const short8*)&Vt[(size_t)(fn0 * 16 + row16) * 128 + kk * 32 + kq * 8];
                short8 A1 = *(const short8*)&Vt[(size_t)(fn1 * 16 + row16) * 128 + kk * 32 + kq * 8];
                c0 = MFMA(A0, Ba[kk], c0, 0, 0, 0);
                c1 = MFMA(A1, Ba[kk], c1, 0, 0, 0);
            }
            #pragma unroll
            for (int h = 0; h < 2; ++h) {
                const int fn = fp * 2 + h;
                f32x4 c = h ? c1 : c0;
                float4 bv = *(const float4*)&vb[fn * 16 + kq * 4];
                ushort4 tw;
                tw.x = f2b(fmaxf(c[0] + bv.x, 0.f));
                tw.y = f2b(fmaxf(c[1] + bv.y, 0.f));
                tw.z = f2b(fmaxf(c[2] + bv.z, 0.f));
                tw.w = f2b(fmaxf(c[3] + bv.w, 0.f));
                *(ushort4*)&t_lds[tl_row][fn * 16 + kq * 4] = tw;
            }
        }

        // ---- out^T = Wt @ concat(xb, t)^T + wb, K=256 ----
        short8 Bx[4], Bt[4];
        #pragma unroll
        for (int kk = 0; kk < 4; ++kk)
            Bx[kk] = *(const short8*)&xb[(size_t)nclamp * D + kk * 32 + kq * 8];
        #pragma unroll
        for (int kk = 0; kk < 4; ++kk)
            Bt[kk] = *(const short8*)&t_lds[tl_row][kk * 32 + kq * 8];  // same-wave dep, lgkmcnt

        #pragma unroll
        for (int fp = 0; fp < 4; ++fp) {
            const int fn0 = fp * 2, fn1 = fp * 2 + 1;
            f32x4 c0 = {0.f, 0.f, 0.f, 0.f}, c1 = {0.f, 0.f, 0.f, 0.f};
            #pragma unroll
            for (int kk = 0; kk < 4; ++kk) {
                short8 A0 = *(const short8*)&Wt[(size_t)(fn0 * 16 + row16) * 256 + kk * 32 + kq * 8];
                short8 A1 = *(const short8*)&Wt[(size_t)(fn1 * 16 + row16) * 256 + kk * 32 + kq * 8];
                c0 = MFMA(A0, Bx[kk], c0, 0, 0, 0);
                c1 = MFMA(A1, Bx[kk], c1, 0, 0, 0);
            }
            #pragma unroll
            for (int kk = 0; kk < 4; ++kk) {
                short8 A0 = *(const short8*)&Wt[(size_t)(fn0 * 16 + row16) * 256 + 128 + kk * 32 + kq * 8];
                short8 A1 = *(const short8*)&Wt[(size_t)(fn1 * 16 + row16) * 256 + 128 + kk * 32 + kq * 8];
                c0 = MFMA(A0, Bt[kk], c0, 0, 0, 0);
                c1 = MFMA(A1, Bt[kk], c1, 0, 0, 0);
            }
            #pragma unroll
            for (int h = 0; h < 2; ++h) {
                const int fn = fp * 2 + h;
                f32x4 c = h ? c1 : c0;
                float4 bv = *(const float4*)&wb[fn * 16 + kq * 4];
                float o0 = c[0] + bv.x, o1 = c[1] + bv.y, o2 = c[2] + bv.z, o3 = c[3] + bv.w;
                if (xb_out) {  // layer 0: relu + bf16, in-place
                    if (node < n_nodes) {
                        ushort4 ow;
                        ow.x = f2b(fmaxf(o0, 0.f));
                        ow.y = f2b(fmaxf(o1, 0.f));
                        ow.z = f2b(fmaxf(o2, 0.f));
                        ow.w = f2b(fmaxf(o3, 0.f));
                        *(ushort4*)&xb_out[(size_t)node * D + fn * 16 + kq * 4] = ow;
                    }
                } else {       // layer 1: fp32 final output
                    if (node < n_nodes) {
                        float4 ow = make_float4(o0, o1, o2, o3);
                        *(float4*)&f_out[(size_t)node * D + fn * 16 + kq * 4] = ow;
                    }
                }
            }
        }
    }
}

extern "C" void kernel_launch(void* const* d_in, const int* in_sizes, int n_in,
                              void* d_out, int out_size, void* d_ws, size_t ws_size,
                              hipStream_t stream)
{
    const int* edge_index      = (const int*)d_in[0];
    const int* user_features   = (const int*)d_in[1];
    const int* item_features   = (const int*)d_in[2];
    const int* user_text       = (const int*)d_in[3];
    const int* item_text       = (const int*)d_in[4];
    const float* user_id_emb   = (const float*)d_in[5];
    const float* item_id_emb   = (const float*)d_in[6];
    const float* user_feat_emb = (const float*)d_in[7];
    const float* item_feat_emb = (const float*)d_in[8];
    const float* word_emb      = (const float*)d_in[9];
    const float* user_projW    = (const float*)d_in[10];
    const float* user_projb    = (const float*)d_in[11];
    const float* item_projW    = (const float*)d_in[12];
    const float* item_projb    = (const float*)d_in[13];
    const float* w0W = (const float*)d_in[14];
    const float* w0b = (const float*)d_in[15];
    const float* w1W = (const float*)d_in[16];
    const float* w1b = (const float*)d_in[17];
    const float* v0W = (const float*)d_in[18];
    const float* v0b = (const float*)d_in[19];
    const float* v1W = (const float*)d_in[20];
    const float* v1b = (const float*)d_in[21];

    const int E  = in_sizes[0] / 2;
    const int NU = in_sizes[5] / D;
    const int NI = in_sizes[6] / D;
    const int N  = NU + NI;
    const int NB = (N + 1023) / 1024;

    // workspace layout
    u16* xb   = (u16*)d_ws;                       // [N,128] bf16
    u16* aggm = xb + (size_t)N * D;               // [N,128] bf16
    u16* Vt0  = aggm + (size_t)N * D;             // [128,128]
    u16* Vt1  = Vt0 + 128 * 128;
    u16* Wt0  = Vt1 + 128 * 128;                  // [128,256]
    u16* Wt1  = Wt0 + 256 * 128;
    int* row_ptr = (int*)(Wt1 + 256 * 128);       // [N+1]
    int* deg_i   = row_ptr + (N + 1);             // [N]
    int* cursor  = deg_i + N;                     // [N]
    int* bsums   = cursor + N;                    // [256]
    int* ebuf    = bsums + 256;                   // [E]

    hipMemsetAsync(deg_i, 0, (size_t)(2 * N) * sizeof(int), stream);

    const int* src = edge_index;
    const int* dst = edge_index + E;
    dim3 blk(256);

    // weight convert+transpose (tiny)
    transpose_bf16_kernel<<<(128 * 128 + 255) / 256, blk, 0, stream>>>(v0W, Vt0, 128, 128);
    transpose_bf16_kernel<<<(128 * 128 + 255) / 256, blk, 0, stream>>>(v1W, Vt1, 128, 128);
    transpose_bf16_kernel<<<(256 * 128 + 255) / 256, blk, 0, stream>>>(w0W, Wt0, 256, 128);
    transpose_bf16_kernel<<<(256 * 128 + 255) / 256, blk, 0, stream>>>(w1W, Wt1, 256, 128);

    init_nodes_kernel<<<(NU + NPB - 1) / NPB, blk, 0, stream>>>(
        user_features, user_text, user_feat_emb, word_emb,
        user_projW, user_projb, user_id_emb, xb, NU, 0);
    init_nodes_kernel<<<(NI + NPB - 1) / NPB, blk, 0, stream>>>(
        item_features, item_text, item_feat_emb, word_emb,
        item_projW, item_projb, item_id_emb, xb, NI, NU);

    // CSR build
    hist_kernel<<<(E + 255) / 256, blk, 0, stream>>>(dst, E, deg_i);
    scan1_kernel<<<NB, blk, 0, stream>>>(deg_i, N, row_ptr, bsums);
    scan2_kernel<<<1, blk, 0, stream>>>(bsums, NB);
    scan3_kernel<<<NB, blk, 0, stream>>>(row_ptr, bsums, N, E);
    fill_kernel<<<(E + 255) / 256, blk, 0, stream>>>(src, dst, E, row_ptr, cursor, ebuf);

    const int sage_grid = (N + 127) / 128;

    // layer 0 (relu, bf16 in-place)
    aggregate_kernel<<<(N + 3) / 4, blk, 0, stream>>>(row_ptr, ebuf, xb, aggm, N);
    sage_mfma_kernel<<<sage_grid, blk, 0, stream>>>(
        xb, aggm, Vt0, v0b, Wt0, w0b, xb, nullptr, N);

    // layer 1 (no relu, fp32 -> d_out)
    aggregate_kernel<<<(N + 3) / 4, blk, 0, stream>>>(row_ptr, ebuf, xb, aggm, N);
    sage_mfma_kernel<<<sage_grid, blk, 0, stream>>>(
        xb, aggm, Vt1, v1b, Wt1, w1b, nullptr, (float*)d_out, N);
}

// Round 7
// 1134.882 us; speedup vs baseline: 5.6386x; 1.1583x over previous
//
#include <hip/hip_runtime.h>

#define D 128
#define HALF 64
constexpr int INB = 32;   // nodes per init block

typedef __attribute__((ext_vector_type(8))) short short8;
typedef __attribute__((ext_vector_type(4))) float f32x4;
typedef unsigned short u16;
typedef unsigned int u32;

__device__ __forceinline__ u16 f2b(float f) {
    u32 u = __builtin_bit_cast(u32, f);
    u32 r = (u + 0x7fffu + ((u >> 16) & 1u)) >> 16;
    return (u16)r;
}
__device__ __forceinline__ float b2f_lo(u32 v) { return __builtin_bit_cast(float, v << 16); }
__device__ __forceinline__ float b2f_hi(u32 v) { return __builtin_bit_cast(float, v & 0xffff0000u); }

#define MFMA __builtin_amdgcn_mfma_f32_16x16x32_bf16

// ---------------- weight transpose+convert: out[n][k] = (bf16)in[k][n] ----------------
__global__ __launch_bounds__(256) void transpose_bf16_kernel(
    const float* __restrict__ in, u16* __restrict__ out, int K, int N)
{
    int idx = blockIdx.x * 256 + threadIdx.x;
    if (idx >= K * N) return;
    int k = idx / N, n = idx % N;
    out[(size_t)n * K + k] = f2b(in[idx]);
}

// ---------------- init: gather + mean -> bf16 LDS, then MFMA [320->128] proj ----------------
// A-frag: lane holds Pt row (fn*16 + l&15), k=(l>>4)*8..+7 (16B, global, L2-hot)
// B-frag: lane holds node row (l&15), same k slice (ds_read_b128 from in_s)
// C-frag: col = l&15 (node), row = (l>>4)*4+r (out dim)   [same convention as sage, m89-verified]
__global__ __launch_bounds__(256) void init_mfma_kernel(
    const int* __restrict__ feat_ids,      // [n,10]
    const int* __restrict__ text_ids,      // [n,3,8]
    const float* __restrict__ feat_emb,    // [*,128]
    const float* __restrict__ word_emb,    // [30000,64]
    const u16* __restrict__ Pt,            // [128][320] bf16 = projW^T
    const float* __restrict__ projb,       // [128]
    const float* __restrict__ id_emb,      // [n,128]
    u16* __restrict__ xb,                  // bf16 rows (out_base+g)
    int n_nodes, int out_base)
{
    __shared__ u16 in_s[INB][328];   // 328 u16 row: stride 164 dwords == 4 mod 32 -> 2-way max
    __shared__ int fid_s[INB][10];
    __shared__ int tid_s[INB][24];
    const int base = blockIdx.x * INB;
    const int t = threadIdx.x;

    for (int i = t; i < INB * 10; i += 256) {
        int node = i / 10, j = i % 10;
        int g = base + node; if (g > n_nodes - 1) g = n_nodes - 1;
        fid_s[node][j] = feat_ids[(size_t)g * 10 + j];
    }
    for (int i = t; i < INB * 24; i += 256) {
        int node = i / 24, j = i % 24;
        int g = base + node; if (g > n_nodes - 1) g = n_nodes - 1;
        tid_s[node][j] = text_ids[(size_t)g * 24 + j];
    }
    __syncthreads();

    // feat mean -> in_s[node][0..127]
    for (int i = t; i < INB * 128; i += 256) {
        int node = i >> 7, d = i & 127;
        float acc = 0.f;
        #pragma unroll
        for (int j = 0; j < 10; ++j) acc += feat_emb[(size_t)fid_s[node][j] * D + d];
        in_s[node][d] = f2b(acc * 0.1f);
    }
    // text field means -> in_s[node][128..319]
    for (int i = t; i < INB * 192; i += 256) {
        int node = i / 192, tt = i % 192;
        int f = tt >> 6, d2 = tt & 63;
        float acc = 0.f;
        #pragma unroll
        for (int w = 0; w < 8; ++w) acc += word_emb[(size_t)tid_s[node][f * 8 + w] * HALF + d2];
        in_s[node][128 + tt] = f2b(acc * 0.125f);
    }
    __syncthreads();

    // ---- out^T = Pt @ in^T (K=320), fused +projb +id_emb, bf16 store ----
    const int wid = t >> 6, lane = t & 63;
    const int row16 = lane & 15, kq = lane >> 4;
    const int g2 = wid >> 1;          // node group (0/1): 16 nodes each
    const int oh = wid & 1;           // output half (dims oh*64 .. +63)
    const int lnode = g2 * 16 + row16;
    const int node = base + lnode;

    short8 Bfrag[10];
    #pragma unroll
    for (int kk = 0; kk < 10; ++kk)
        Bfrag[kk] = *(const short8*)&in_s[lnode][kk * 32 + kq * 8];

    #pragma unroll
    for (int fp = 0; fp < 4; ++fp) {
        const int fn = oh * 4 + fp;
        f32x4 c = {0.f, 0.f, 0.f, 0.f};
        #pragma unroll
        for (int kk = 0; kk < 10; ++kk) {
            short8 A = *(const short8*)&Pt[(size_t)(fn * 16 + row16) * 320 + kk * 32 + kq * 8];
            c = MFMA(A, Bfrag[kk], c, 0, 0, 0);
        }
        if (node < n_nodes) {
            float4 bv = *(const float4*)&projb[fn * 16 + kq * 4];
            float4 ie = *(const float4*)&id_emb[(size_t)node * D + fn * 16 + kq * 4];
            ushort4 ow;
            ow.x = f2b(c[0] + bv.x + ie.x);
            ow.y = f2b(c[1] + bv.y + ie.y);
            ow.z = f2b(c[2] + bv.z + ie.z);
            ow.w = f2b(c[3] + bv.w + ie.w);
            *(ushort4*)&xb[(size_t)(out_base + node) * D + fn * 16 + kq * 4] = ow;
        }
    }
}

// ---------------- CSR build ----------------
__global__ __launch_bounds__(256) void hist_kernel(
    const int* __restrict__ dst, int E, int* __restrict__ deg)
{
    int e = blockIdx.x * 256 + threadIdx.x;
    if (e < E) atomicAdd(&deg[dst[e]], 1);
}

__global__ __launch_bounds__(256) void scan1_kernel(
    const int* __restrict__ deg, int n, int* __restrict__ out_ex, int* __restrict__ bsums)
{
    __shared__ int s[256];
    const int t = threadIdx.x;
    const int base = blockIdx.x * 1024 + t * 4;
    int v0 = 0, v1 = 0, v2 = 0, v3 = 0;
    if (base + 0 < n) v0 = deg[base + 0];
    if (base + 1 < n) v1 = deg[base + 1];
    if (base + 2 < n) v2 = deg[base + 2];
    if (base + 3 < n) v3 = deg[base + 3];
    int sum = v0 + v1 + v2 + v3;
    s[t] = sum;
    __syncthreads();
    for (int off = 1; off < 256; off <<= 1) {
        int tmp = (t >= off) ? s[t - off] : 0;
        __syncthreads();
        s[t] += tmp;
        __syncthreads();
    }
    int ex = s[t] - sum;
    if (t == 255) bsums[blockIdx.x] = s[255];
    if (base + 0 < n) out_ex[base + 0] = ex;
    if (base + 1 < n) out_ex[base + 1] = ex + v0;
    if (base + 2 < n) out_ex[base + 2] = ex + v0 + v1;
    if (base + 3 < n) out_ex[base + 3] = ex + v0 + v1 + v2;
}

__global__ __launch_bounds__(256) void scan2_kernel(int* __restrict__ bsums, int nb)
{
    __shared__ int s[256];
    const int t = threadIdx.x;
    int v = (t < nb) ? bsums[t] : 0;
    s[t] = v;
    __syncthreads();
    for (int off = 1; off < 256; off <<= 1) {
        int tmp = (t >= off) ? s[t - off] : 0;
        __syncthreads();
        s[t] += tmp;
        __syncthreads();
    }
    if (t < nb) bsums[t] = s[t] - v;
}

__global__ __launch_bounds__(256) void scan3_kernel(
    int* __restrict__ row_ptr, const int* __restrict__ bsums, int n, int E)
{
    const int add = bsums[blockIdx.x];
    const int base = blockIdx.x * 1024 + threadIdx.x * 4;
    #pragma unroll
    for (int j = 0; j < 4; ++j)
        if (base + j < n) row_ptr[base + j] += add;
    if (blockIdx.x == 0 && threadIdx.x == 0) row_ptr[n] = E;
}

__global__ __launch_bounds__(256) void fill_kernel(
    const int* __restrict__ src, const int* __restrict__ dst, int E,
    const int* __restrict__ row_ptr, int* __restrict__ cursor, int* __restrict__ ebuf)
{
    int e = blockIdx.x * 256 + threadIdx.x;
    if (e < E) {
        int d = dst[e];
        int slot = atomicAdd(&cursor[d], 1);
        ebuf[row_ptr[d] + slot] = src[e];
    }
}

// ---------------- gather aggregate (bf16): aggm[g] = mean x[src] ----------------
__global__ __launch_bounds__(256) void aggregate_kernel(
    const int* __restrict__ row_ptr, const int* __restrict__ ebuf,
    const u16* __restrict__ xb, u16* __restrict__ aggm, int n_nodes)
{
    const int wave = threadIdx.x >> 6;
    const int lane = threadIdx.x & 63;
    const int g = blockIdx.x * 4 + wave;
    if (g >= n_nodes) return;
    const int s0 = row_ptr[g], s1 = row_ptr[g + 1];
    float ax = 0.f, ay = 0.f;
    for (int e = s0; e < s1; ++e) {
        int s = ebuf[e];
        u32 v = *(const u32*)&xb[(size_t)s * D + lane * 2];
        ax += b2f_lo(v);
        ay += b2f_hi(v);
    }
    const float inv = 1.0f / fmaxf((float)(s1 - s0), 1.0f);
    u32 o = (u32)f2b(ax * inv) | ((u32)f2b(ay * inv) << 16);
    *(u32*)&aggm[(size_t)g * D + lane * 2] = o;
}

// ---------------- SAGE layer via MFMA (transposed GEMMs) ----------------
__global__ __launch_bounds__(256) void sage_mfma_kernel(
    const u16* __restrict__ xb, const u16* __restrict__ aggm,
    const u16* __restrict__ Vt,  const float* __restrict__ vb,   // Vt [128][128]
    const u16* __restrict__ Wt,  const float* __restrict__ wb,   // Wt [128][256]
    u16* __restrict__ xb_out,    // layer0: write bf16 in place (else null)
    float* __restrict__ f_out,   // layer1: write fp32 d_out (else null)
    int n_nodes)
{
    __shared__ u16 t_lds[128][136];
    const int wid  = threadIdx.x >> 6;
    const int lane = threadIdx.x & 63;
    const int row16 = lane & 15;
    const int kq    = lane >> 4;
    const int nb = blockIdx.x * 128 + wid * 32;

    #pragma unroll
    for (int g = 0; g < 2; ++g) {
        const int node = nb + g * 16 + row16;
        const int nclamp = node < n_nodes ? node : n_nodes - 1;
        const int tl_row = wid * 32 + g * 16 + row16;

        // ---- t^T = relu(Vt @ agg^T + vb), K=128 ----
        short8 Ba[4];
        #pragma unroll
        for (int kk = 0; kk < 4; ++kk)
            Ba[kk] = *(const short8*)&aggm[(size_t)nclamp * D + kk * 32 + kq * 8];
        #pragma unroll
        for (int fp = 0; fp < 4; ++fp) {
            const int fn0 = fp * 2, fn1 = fp * 2 + 1;
            f32x4 c0 = {0.f, 0.f, 0.f, 0.f}, c1 = {0.f, 0.f, 0.f, 0.f};
            #pragma unroll
            for (int kk = 0; kk < 4; ++kk) {
                short8 A0 = *(const short8*)&Vt[(size_t)(fn0 * 16 + row16) * 128 + kk * 32 + kq * 8];
                short8 A1 = *(const short8*)&Vt[(size_t)(fn1 * 16 + row16) * 128 + kk * 32 + kq * 8];
                c0 = MFMA(A0, Ba[kk], c0, 0, 0, 0);
                c1 = MFMA(A1, Ba[kk], c1, 0, 0, 0);
            }
            #pragma unroll
            for (int h = 0; h < 2; ++h) {
                const int fn = fp * 2 + h;
                f32x4 c = h ? c1 : c0;
                float4 bv = *(const float4*)&vb[fn * 16 + kq * 4];
                ushort4 tw;
                tw.x = f2b(fmaxf(c[0] + bv.x, 0.f));
                tw.y = f2b(fmaxf(c[1] + bv.y, 0.f));
                tw.z = f2b(fmaxf(c[2] + bv.z, 0.f));
                tw.w = f2b(fmaxf(c[3] + bv.w, 0.f));
                *(ushort4*)&t_lds[tl_row][fn * 16 + kq * 4] = tw;
            }
        }

        // ---- out^T = Wt @ concat(xb, t)^T + wb, K=256 ----
        short8 Bx[4], Bt[4];
        #pragma unroll
        for (int kk = 0; kk < 4; ++kk)
            Bx[kk] = *(const short8*)&xb[(size_t)nclamp * D + kk * 32 + kq * 8];
        #pragma unroll
        for (int kk = 0; kk < 4; ++kk)
            Bt[kk] = *(const short8*)&t_lds[tl_row][kk * 32 + kq * 8];

        #pragma unroll
        for (int fp = 0; fp < 4; ++fp) {
            const int fn0 = fp * 2, fn1 = fp * 2 + 1;
            f32x4 c0 = {0.f, 0.f, 0.f, 0.f}, c1 = {0.f, 0.f, 0.f, 0.f};
            #pragma unroll
            for (int kk = 0; kk < 4; ++kk) {
                short8 A0 = *(const short8*)&Wt[(size_t)(fn0 * 16 + row16) * 256 + kk * 32 + kq * 8];
                short8 A1 = *(const short8*)&Wt[(size_t)(fn1 * 16 + row16) * 256 + kk * 32 + kq * 8];
                c0 = MFMA(A0, Bx[kk], c0, 0, 0, 0);
                c1 = MFMA(A1, Bx[kk], c1, 0, 0, 0);
            }
            #pragma unroll
            for (int kk = 0; kk < 4; ++kk) {
                short8 A0 = *(const short8*)&Wt[(size_t)(fn0 * 16 + row16) * 256 + 128 + kk * 32 + kq * 8];
                short8 A1 = *(const short8*)&Wt[(size_t)(fn1 * 16 + row16) * 256 + 128 + kk * 32 + kq * 8];
                c0 = MFMA(A0, Bt[kk], c0, 0, 0, 0);
                c1 = MFMA(A1, Bt[kk], c1, 0, 0, 0);
            }
            #pragma unroll
            for (int h = 0; h < 2; ++h) {
                const int fn = fp * 2 + h;
                f32x4 c = h ? c1 : c0;
                float4 bv = *(const float4*)&wb[fn * 16 + kq * 4];
                float o0 = c[0] + bv.x, o1 = c[1] + bv.y, o2 = c[2] + bv.z, o3 = c[3] + bv.w;
                if (xb_out) {
                    if (node < n_nodes) {
                        ushort4 ow;
                        ow.x = f2b(fmaxf(o0, 0.f));
                        ow.y = f2b(fmaxf(o1, 0.f));
                        ow.z = f2b(fmaxf(o2, 0.f));
                        ow.w = f2b(fmaxf(o3, 0.f));
                        *(ushort4*)&xb_out[(size_t)node * D + fn * 16 + kq * 4] = ow;
                    }
                } else {
                    if (node < n_nodes) {
                        float4 ow = make_float4(o0, o1, o2, o3);
                        *(float4*)&f_out[(size_t)node * D + fn * 16 + kq * 4] = ow;
                    }
                }
            }
        }
    }
}

extern "C" void kernel_launch(void* const* d_in, const int* in_sizes, int n_in,
                              void* d_out, int out_size, void* d_ws, size_t ws_size,
                              hipStream_t stream)
{
    const int* edge_index      = (const int*)d_in[0];
    const int* user_features   = (const int*)d_in[1];
    const int* item_features   = (const int*)d_in[2];
    const int* user_text       = (const int*)d_in[3];
    const int* item_text       = (const int*)d_in[4];
    const float* user_id_emb   = (const float*)d_in[5];
    const float* item_id_emb   = (const float*)d_in[6];
    const float* user_feat_emb = (const float*)d_in[7];
    const float* item_feat_emb = (const float*)d_in[8];
    const float* word_emb      = (const float*)d_in[9];
    const float* user_projW    = (const float*)d_in[10];
    const float* user_projb    = (const float*)d_in[11];
    const float* item_projW    = (const float*)d_in[12];
    const float* item_projb    = (const float*)d_in[13];
    const float* w0W = (const float*)d_in[14];
    const float* w0b = (const float*)d_in[15];
    const float* w1W = (const float*)d_in[16];
    const float* w1b = (const float*)d_in[17];
    const float* v0W = (const float*)d_in[18];
    const float* v0b = (const float*)d_in[19];
    const float* v1W = (const float*)d_in[20];
    const float* v1b = (const float*)d_in[21];

    const int E  = in_sizes[0] / 2;
    const int NU = in_sizes[5] / D;
    const int NI = in_sizes[6] / D;
    const int N  = NU + NI;
    const int NB = (N + 1023) / 1024;

    // workspace layout
    u16* xb   = (u16*)d_ws;                       // [N,128] bf16
    u16* aggm = xb + (size_t)N * D;               // [N,128] bf16
    u16* Vt0  = aggm + (size_t)N * D;             // [128,128]
    u16* Vt1  = Vt0 + 128 * 128;
    u16* Wt0  = Vt1 + 128 * 128;                  // [128,256]
    u16* Wt1  = Wt0 + 256 * 128;
    u16* Pt_u = Wt1 + 256 * 128;                  // [128,320]
    u16* Pt_i = Pt_u + 128 * 320;                 // [128,320]
    int* row_ptr = (int*)(Pt_i + 128 * 320);      // [N+1]
    int* deg_i   = row_ptr + (N + 1);             // [N]
    int* cursor  = deg_i + N;                     // [N]
    int* bsums   = cursor + N;                    // [256]
    int* ebuf    = bsums + 256;                   // [E]

    hipMemsetAsync(deg_i, 0, (size_t)(2 * N) * sizeof(int), stream);

    const int* src = edge_index;
    const int* dst = edge_index + E;
    dim3 blk(256);

    // weight convert+transpose (tiny)
    transpose_bf16_kernel<<<(128 * 128 + 255) / 256, blk, 0, stream>>>(v0W, Vt0, 128, 128);
    transpose_bf16_kernel<<<(128 * 128 + 255) / 256, blk, 0, stream>>>(v1W, Vt1, 128, 128);
    transpose_bf16_kernel<<<(256 * 128 + 255) / 256, blk, 0, stream>>>(w0W, Wt0, 256, 128);
    transpose_bf16_kernel<<<(256 * 128 + 255) / 256, blk, 0, stream>>>(w1W, Wt1, 256, 128);
    transpose_bf16_kernel<<<(320 * 128 + 255) / 256, blk, 0, stream>>>(user_projW, Pt_u, 320, 128);
    transpose_bf16_kernel<<<(320 * 128 + 255) / 256, blk, 0, stream>>>(item_projW, Pt_i, 320, 128);

    init_mfma_kernel<<<(NU + INB - 1) / INB, blk, 0, stream>>>(
        user_features, user_text, user_feat_emb, word_emb,
        Pt_u, user_projb, user_id_emb, xb, NU, 0);
    init_mfma_kernel<<<(NI + INB - 1) / INB, blk, 0, stream>>>(
        item_features, item_text, item_feat_emb, word_emb,
        Pt_i, item_projb, item_id_emb, xb, NI, NU);

    // CSR build
    hist_kernel<<<(E + 255) / 256, blk, 0, stream>>>(dst, E, deg_i);
    scan1_kernel<<<NB, blk, 0, stream>>>(deg_i, N, row_ptr, bsums);
    scan2_kernel<<<1, blk, 0, stream>>>(bsums, NB);
    scan3_kernel<<<NB, blk, 0, stream>>>(row_ptr, bsums, N, E);
    fill_kernel<<<(E + 255) / 256, blk, 0, stream>>>(src, dst, E, row_ptr, cursor, ebuf);

    const int sage_grid = (N + 127) / 128;

    // layer 0 (relu, bf16 in-place)
    aggregate_kernel<<<(N + 3) / 4, blk, 0, stream>>>(row_ptr, ebuf, xb, aggm, N);
    sage_mfma_kernel<<<sage_grid, blk, 0, stream>>>(
        xb, aggm, Vt0, v0b, Wt0, w0b, xb, nullptr, N);

    // layer 1 (no relu, fp32 -> d_out)
    aggregate_kernel<<<(N + 3) / 4, blk, 0, stream>>>(row_ptr, ebuf, xb, aggm, N);
    sage_mfma_kernel<<<sage_grid, blk, 0, stream>>>(
        xb, aggm, Vt1, v1b, Wt1, w1b, nullptr, (float*)d_out, N);
}

// Round 10
// 1077.238 us; speedup vs baseline: 5.9404x; 1.0535x over previous
//
#include <hip/hip_runtime.h>

#define D 128
#define HALF 64
constexpr int INB = 32;   // nodes per init block

typedef __attribute__((ext_vector_type(8))) short short8;
typedef __attribute__((ext_vector_type(4))) float f32x4;
typedef unsigned short u16;
typedef unsigned int u32;

__device__ __forceinline__ u16 f2b(float f) {
    u32 u = __builtin_bit_cast(u32, f);
    u32 r = (u + 0x7fffu + ((u >> 16) & 1u)) >> 16;
    return (u16)r;
}
__device__ __forceinline__ float b2f_lo(u32 v) { return __builtin_bit_cast(float, v << 16); }
__device__ __forceinline__ float b2f_hi(u32 v) { return __builtin_bit_cast(float, v & 0xffff0000u); }

#define MFMA __builtin_amdgcn_mfma_f32_16x16x32_bf16

// ---------------- weight transpose+convert: out[n][k] = (bf16)in[k][n] ----------------
__global__ __launch_bounds__(256) void transpose_bf16_kernel(
    const float* __restrict__ in, u16* __restrict__ out, int K, int N)
{
    int idx = blockIdx.x * 256 + threadIdx.x;
    if (idx >= K * N) return;
    int k = idx / N, n = idx % N;
    out[(size_t)n * K + k] = f2b(in[idx]);
}

// ---------------- init: gather + mean -> bf16 LDS, then MFMA [320->128] proj ----------------
__global__ __launch_bounds__(256) void init_mfma_kernel(
    const int* __restrict__ feat_ids,      // [n,10]
    const int* __restrict__ text_ids,      // [n,3,8]
    const float* __restrict__ feat_emb,    // [*,128]
    const float* __restrict__ word_emb,    // [30000,64]
    const u16* __restrict__ Pt,            // [128][320] bf16 = projW^T
    const float* __restrict__ projb,       // [128]
    const float* __restrict__ id_emb,      // [n,128]
    u16* __restrict__ xb,                  // bf16 rows (out_base+g)
    int n_nodes, int out_base)
{
    __shared__ u16 in_s[INB][328];
    __shared__ int fid_s[INB][10];
    __shared__ int tid_s[INB][24];
    const int base = blockIdx.x * INB;
    const int t = threadIdx.x;

    for (int i = t; i < INB * 10; i += 256) {
        int node = i / 10, j = i % 10;
        int g = base + node; if (g > n_nodes - 1) g = n_nodes - 1;
        fid_s[node][j] = feat_ids[(size_t)g * 10 + j];
    }
    for (int i = t; i < INB * 24; i += 256) {
        int node = i / 24, j = i % 24;
        int g = base + node; if (g > n_nodes - 1) g = n_nodes - 1;
        tid_s[node][j] = text_ids[(size_t)g * 24 + j];
    }
    __syncthreads();

    for (int i = t; i < INB * 128; i += 256) {
        int node = i >> 7, d = i & 127;
        float acc = 0.f;
        #pragma unroll
        for (int j = 0; j < 10; ++j) acc += feat_emb[(size_t)fid_s[node][j] * D + d];
        in_s[node][d] = f2b(acc * 0.1f);
    }
    for (int i = t; i < INB * 192; i += 256) {
        int node = i / 192, tt = i % 192;
        int f = tt >> 6, d2 = tt & 63;
        float acc = 0.f;
        #pragma unroll
        for (int w = 0; w < 8; ++w) acc += word_emb[(size_t)tid_s[node][f * 8 + w] * HALF + d2];
        in_s[node][128 + tt] = f2b(acc * 0.125f);
    }
    __syncthreads();

    const int wid = t >> 6, lane = t & 63;
    const int row16 = lane & 15, kq = lane >> 4;
    const int g2 = wid >> 1;
    const int oh = wid & 1;
    const int lnode = g2 * 16 + row16;
    const int node = base + lnode;

    short8 Bfrag[10];
    #pragma unroll
    for (int kk = 0; kk < 10; ++kk)
        Bfrag[kk] = *(const short8*)&in_s[lnode][kk * 32 + kq * 8];

    #pragma unroll
    for (int fp = 0; fp < 4; ++fp) {
        const int fn = oh * 4 + fp;
        f32x4 c = {0.f, 0.f, 0.f, 0.f};
        #pragma unroll
        for (int kk = 0; kk < 10; ++kk) {
            short8 A = *(const short8*)&Pt[(size_t)(fn * 16 + row16) * 320 + kk * 32 + kq * 8];
            c = MFMA(A, Bfrag[kk], c, 0, 0, 0);
        }
        if (node < n_nodes) {
            float4 bv = *(const float4*)&projb[fn * 16 + kq * 4];
            float4 ie = *(const float4*)&id_emb[(size_t)node * D + fn * 16 + kq * 4];
            ushort4 ow;
            ow.x = f2b(c[0] + bv.x + ie.x);
            ow.y = f2b(c[1] + bv.y + ie.y);
            ow.z = f2b(c[2] + bv.z + ie.z);
            ow.w = f2b(c[3] + bv.w + ie.w);
            *(ushort4*)&xb[(size_t)(out_base + node) * D + fn * 16 + kq * 4] = ow;
        }
    }
}

// ---------------- CSR build ----------------
__global__ __launch_bounds__(256) void hist_kernel(
    const int* __restrict__ dst, int E, int* __restrict__ deg)
{
    int e = blockIdx.x * 256 + threadIdx.x;
    if (e < E) atomicAdd(&deg[dst[e]], 1);
}

__global__ __launch_bounds__(256) void scan1_kernel(
    const int* __restrict__ deg, int n, int* __restrict__ out_ex, int* __restrict__ bsums)
{
    __shared__ int s[256];
    const int t = threadIdx.x;
    const int base = blockIdx.x * 1024 + t * 4;
    int v0 = 0, v1 = 0, v2 = 0, v3 = 0;
    if (base + 0 < n) v0 = deg[base + 0];
    if (base + 1 < n) v1 = deg[base + 1];
    if (base + 2 < n) v2 = deg[base + 2];
    if (base + 3 < n) v3 = deg[base + 3];
    int sum = v0 + v1 + v2 + v3;
    s[t] = sum;
    __syncthreads();
    for (int off = 1; off < 256; off <<= 1) {
        int tmp = (t >= off) ? s[t - off] : 0;
        __syncthreads();
        s[t] += tmp;
        __syncthreads();
    }
    int ex = s[t] - sum;
    if (t == 255) bsums[blockIdx.x] = s[255];
    if (base + 0 < n) out_ex[base + 0] = ex;
    if (base + 1 < n) out_ex[base + 1] = ex + v0;
    if (base + 2 < n) out_ex[base + 2] = ex + v0 + v1;
    if (base + 3 < n) out_ex[base + 3] = ex + v0 + v1 + v2;
}

__global__ __launch_bounds__(256) void scan2_kernel(int* __restrict__ bsums, int nb)
{
    __shared__ int s[256];
    const int t = threadIdx.x;
    int v = (t < nb) ? bsums[t] : 0;
    s[t] = v;
    __syncthreads();
    for (int off = 1; off < 256; off <<= 1) {
        int tmp = (t >= off) ? s[t - off] : 0;
        __syncthreads();
        s[t] += tmp;
        __syncthreads();
    }
    if (t < nb) bsums[t] = s[t] - v;
}

__global__ __launch_bounds__(256) void scan3_kernel(
    int* __restrict__ row_ptr, const int* __restrict__ bsums, int n, int E)
{
    const int add = bsums[blockIdx.x];
    const int base = blockIdx.x * 1024 + threadIdx.x * 4;
    #pragma unroll
    for (int j = 0; j < 4; ++j)
        if (base + j < n) row_ptr[base + j] += add;
    if (blockIdx.x == 0 && threadIdx.x == 0) row_ptr[n] = E;
}

__global__ __launch_bounds__(256) void fill_kernel(
    const int* __restrict__ src, const int* __restrict__ dst, int E,
    const int* __restrict__ row_ptr, int* __restrict__ cursor, int* __restrict__ ebuf)
{
    int e = blockIdx.x * 256 + threadIdx.x;
    if (e < E) {
        int d = dst[e];
        int slot = atomicAdd(&cursor[d], 1);
        ebuf[row_ptr[d] + slot] = src[e];
    }
}

// ---------------- gather aggregate (bf16): aggm[g] = mean x[src] ----------------
__global__ __launch_bounds__(256) void aggregate_kernel(
    const int* __restrict__ row_ptr, const int* __restrict__ ebuf,
    const u16* __restrict__ xb, u16* __restrict__ aggm, int n_nodes)
{
    const int wave = threadIdx.x >> 6;
    const int lane = threadIdx.x & 63;
    const int g = blockIdx.x * 4 + wave;
    if (g >= n_nodes) return;
    const int s0 = row_ptr[g], s1 = row_ptr[g + 1];
    float ax = 0.f, ay = 0.f;
    for (int e = s0; e < s1; ++e) {
        int s = ebuf[e];
        u32 v = *(const u32*)&xb[(size_t)s * D + lane * 2];
        ax += b2f_lo(v);
        ay += b2f_hi(v);
    }
    const float inv = 1.0f / fmaxf((float)(s1 - s0), 1.0f);
    u32 o = (u32)f2b(ax * inv) | ((u32)f2b(ay * inv) << 16);
    *(u32*)&aggm[(size_t)g * D + lane * 2] = o;
}

// ---------------- SAGE layer via MFMA, fn-split across 8 waves ----------------
// Block: 512 thr = 8 waves, 32 nodes. Wave w owns out-dims [w*16, w*16+16).
// RACE FIX (R8): every wave reads ALL 32 nodes' xb rows (Bx) but writes a 16-dim
// slice of every node. All xb reads are hoisted into registers BEFORE the single
// __syncthreads(); all xb writes happen after it. The same barrier also orders
// t_lds writes (V phase) vs t_lds reads (W phase).
__global__ __launch_bounds__(512, 4) void sage_mfma_kernel(
    const u16* __restrict__ xb, const u16* __restrict__ aggm,
    const u16* __restrict__ Vt,  const float* __restrict__ vb,   // Vt [128][128]
    const u16* __restrict__ Wt,  const float* __restrict__ wb,   // Wt [128][256]
    u16* __restrict__ xb_out,    // layer0: write bf16 in place (else null)
    float* __restrict__ f_out,   // layer1: write fp32 d_out (else null)
    int n_nodes)
{
    __shared__ u16 t_lds[32][136];
    const int wid  = threadIdx.x >> 6;   // 0..7 = fn
    const int lane = threadIdx.x & 63;
    const int row16 = lane & 15;
    const int kq    = lane >> 4;
    const int nb = blockIdx.x * 32;

    const int node0 = nb + row16;
    const int node1 = nb + 16 + row16;
    const int ncl0 = node0 < n_nodes ? node0 : n_nodes - 1;
    const int ncl1 = node1 < n_nodes ? node1 : n_nodes - 1;

    // ---- V phase: t^T tile fn=wid for both node groups -> t_lds ----
    short8 Av[4];
    #pragma unroll
    for (int kk = 0; kk < 4; ++kk)
        Av[kk] = *(const short8*)&Vt[(size_t)(wid * 16 + row16) * 128 + kk * 32 + kq * 8];

    #pragma unroll
    for (int g = 0; g < 2; ++g) {
        const int nclamp = g ? ncl1 : ncl0;
        f32x4 c = {0.f, 0.f, 0.f, 0.f};
        #pragma unroll
        for (int kk = 0; kk < 4; ++kk) {
            short8 B = *(const short8*)&aggm[(size_t)nclamp * D + kk * 32 + kq * 8];
            c = MFMA(Av[kk], B, c, 0, 0, 0);
        }
        float4 bv = *(const float4*)&vb[wid * 16 + kq * 4];
        ushort4 tw;
        tw.x = f2b(fmaxf(c[0] + bv.x, 0.f));
        tw.y = f2b(fmaxf(c[1] + bv.y, 0.f));
        tw.z = f2b(fmaxf(c[2] + bv.z, 0.f));
        tw.w = f2b(fmaxf(c[3] + bv.w, 0.f));
        *(ushort4*)&t_lds[g * 16 + row16][wid * 16 + kq * 4] = tw;
    }

    // ---- preload ALL xb reads + W A-frags into registers (before barrier) ----
    short8 Aw[8];
    #pragma unroll
    for (int kk = 0; kk < 8; ++kk)
        Aw[kk] = *(const short8*)&Wt[(size_t)(wid * 16 + row16) * 256 + kk * 32 + kq * 8];

    short8 Bx0[4], Bx1[4];
    #pragma unroll
    for (int kk = 0; kk < 4; ++kk)
        Bx0[kk] = *(const short8*)&xb[(size_t)ncl0 * D + kk * 32 + kq * 8];
    #pragma unroll
    for (int kk = 0; kk < 4; ++kk)
        Bx1[kk] = *(const short8*)&xb[(size_t)ncl1 * D + kk * 32 + kq * 8];

    __syncthreads();   // t_lds ready; all xb reads complete; writes may begin

    // ---- W phase: out^T rows fn=wid, K=256 ----
    #pragma unroll
    for (int g = 0; g < 2; ++g) {
        const int node = g ? node1 : node0;
        f32x4 c = {0.f, 0.f, 0.f, 0.f};
        #pragma unroll
        for (int kk = 0; kk < 4; ++kk)
            c = MFMA(Aw[kk], g ? Bx1[kk] : Bx0[kk], c, 0, 0, 0);
        #pragma unroll
        for (int kk = 0; kk < 4; ++kk) {
            short8 B = *(const short8*)&t_lds[g * 16 + row16][kk * 32 + kq * 8];
            c = MFMA(Aw[4 + kk], B, c, 0, 0, 0);
        }
        if (node < n_nodes) {
            float4 bv = *(const float4*)&wb[wid * 16 + kq * 4];
            float o0 = c[0] + bv.x, o1 = c[1] + bv.y, o2 = c[2] + bv.z, o3 = c[3] + bv.w;
            if (xb_out) {
                ushort4 ow;
                ow.x = f2b(fmaxf(o0, 0.f));
                ow.y = f2b(fmaxf(o1, 0.f));
                ow.z = f2b(fmaxf(o2, 0.f));
                ow.w = f2b(fmaxf(o3, 0.f));
                *(ushort4*)&xb_out[(size_t)node * D + wid * 16 + kq * 4] = ow;
            } else {
                float4 ow = make_float4(o0, o1, o2, o3);
                *(float4*)&f_out[(size_t)node * D + wid * 16 + kq * 4] = ow;
            }
        }
    }
}

extern "C" void kernel_launch(void* const* d_in, const int* in_sizes, int n_in,
                              void* d_out, int out_size, void* d_ws, size_t ws_size,
                              hipStream_t stream)
{
    const int* edge_index      = (const int*)d_in[0];
    const int* user_features   = (const int*)d_in[1];
    const int* item_features   = (const int*)d_in[2];
    const int* user_text       = (const int*)d_in[3];
    const int* item_text       = (const int*)d_in[4];
    const float* user_id_emb   = (const float*)d_in[5];
    const float* item_id_emb   = (const float*)d_in[6];
    const float* user_feat_emb = (const float*)d_in[7];
    const float* item_feat_emb = (const float*)d_in[8];
    const float* word_emb      = (const float*)d_in[9];
    const float* user_projW    = (const float*)d_in[10];
    const float* user_projb    = (const float*)d_in[11];
    const float* item_projW    = (const float*)d_in[12];
    const float* item_projb    = (const float*)d_in[13];
    const float* w0W = (const float*)d_in[14];
    const float* w0b = (const float*)d_in[15];
    const float* w1W = (const float*)d_in[16];
    const float* w1b = (const float*)d_in[17];
    const float* v0W = (const float*)d_in[18];
    const float* v0b = (const float*)d_in[19];
    const float* v1W = (const float*)d_in[20];
    const float* v1b = (const float*)d_in[21];

    const int E  = in_sizes[0] / 2;
    const int NU = in_sizes[5] / D;
    const int NI = in_sizes[6] / D;
    const int N  = NU + NI;
    const int NB = (N + 1023) / 1024;

    // workspace layout
    u16* xb   = (u16*)d_ws;                       // [N,128] bf16
    u16* aggm = xb + (size_t)N * D;               // [N,128] bf16
    u16* Vt0  = aggm + (size_t)N * D;             // [128,128]
    u16* Vt1  = Vt0 + 128 * 128;
    u16* Wt0  = Vt1 + 128 * 128;                  // [128,256]
    u16* Wt1  = Wt0 + 256 * 128;
    u16* Pt_u = Wt1 + 256 * 128;                  // [128,320]
    u16* Pt_i = Pt_u + 128 * 320;                 // [128,320]
    int* row_ptr = (int*)(Pt_i + 128 * 320);      // [N+1]
    int* deg_i   = row_ptr + (N + 1);             // [N]
    int* cursor  = deg_i + N;                     // [N]
    int* bsums   = cursor + N;                    // [256]
    int* ebuf    = bsums + 256;                   // [E]

    hipMemsetAsync(deg_i, 0, (size_t)(2 * N) * sizeof(int), stream);

    const int* src = edge_index;
    const int* dst = edge_index + E;
    dim3 blk(256);

    // weight convert+transpose (tiny)
    transpose_bf16_kernel<<<(128 * 128 + 255) / 256, blk, 0, stream>>>(v0W, Vt0, 128, 128);
    transpose_bf16_kernel<<<(128 * 128 + 255) / 256, blk, 0, stream>>>(v1W, Vt1, 128, 128);
    transpose_bf16_kernel<<<(256 * 128 + 255) / 256, blk, 0, stream>>>(w0W, Wt0, 256, 128);
    transpose_bf16_kernel<<<(256 * 128 + 255) / 256, blk, 0, stream>>>(w1W, Wt1, 256, 128);
    transpose_bf16_kernel<<<(320 * 128 + 255) / 256, blk, 0, stream>>>(user_projW, Pt_u, 320, 128);
    transpose_bf16_kernel<<<(320 * 128 + 255) / 256, blk, 0, stream>>>(item_projW, Pt_i, 320, 128);

    init_mfma_kernel<<<(NU + INB - 1) / INB, blk, 0, stream>>>(
        user_features, user_text, user_feat_emb, word_emb,
        Pt_u, user_projb, user_id_emb, xb, NU, 0);
    init_mfma_kernel<<<(NI + INB - 1) / INB, blk, 0, stream>>>(
        item_features, item_text, item_feat_emb, word_emb,
        Pt_i, item_projb, item_id_emb, xb, NI, NU);

    // CSR build
    hist_kernel<<<(E + 255) / 256, blk, 0, stream>>>(dst, E, deg_i);
    scan1_kernel<<<NB, blk, 0, stream>>>(deg_i, N, row_ptr, bsums);
    scan2_kernel<<<1, blk, 0, stream>>>(bsums, NB);
    scan3_kernel<<<NB, blk, 0, stream>>>(row_ptr, bsums, N, E);
    fill_kernel<<<(E + 255) / 256, blk, 0, stream>>>(src, dst, E, row_ptr, cursor, ebuf);

    const int sage_grid = (N + 31) / 32;
    dim3 sblk(512);

    // layer 0 (relu, bf16 in-place)
    aggregate_kernel<<<(N + 3) / 4, blk, 0, stream>>>(row_ptr, ebuf, xb, aggm, N);
    sage_mfma_kernel<<<sage_grid, sblk, 0, stream>>>(
        xb, aggm, Vt0, v0b, Wt0, w0b, xb, nullptr, N);

    // layer 1 (no relu, fp32 -> d_out)
    aggregate_kernel<<<(N + 3) / 4, blk, 0, stream>>>(row_ptr, ebuf, xb, aggm, N);
    sage_mfma_kernel<<<sage_grid, sblk, 0, stream>>>(
        xb, aggm, Vt1, v1b, Wt1, w1b, nullptr, (float*)d_out, N);
}

// Round 11
// 881.291 us; speedup vs baseline: 7.2611x; 1.2223x over previous
//
#include <hip/hip_runtime.h>

#define D 128
#define HALF 64
constexpr int INB = 32;   // nodes per init block

typedef __attribute__((ext_vector_type(8))) short short8;
typedef __attribute__((ext_vector_type(4))) float f32x4;
typedef unsigned short u16;
typedef unsigned int u32;

__device__ __forceinline__ u16 f2b(float f) {
    u32 u = __builtin_bit_cast(u32, f);
    u32 r = (u + 0x7fffu + ((u >> 16) & 1u)) >> 16;
    return (u16)r;
}
__device__ __forceinline__ float b2f_lo(u32 v) { return __builtin_bit_cast(float, v << 16); }
__device__ __forceinline__ float b2f_hi(u32 v) { return __builtin_bit_cast(float, v & 0xffff0000u); }

#define MFMA __builtin_amdgcn_mfma_f32_16x16x32_bf16

// ---------------- fused weight transpose+convert (6 matrices, one launch) ----------------
// all are [K,128] row-major fp32 -> [128,K] bf16
__global__ __launch_bounds__(256) void transpose_all_kernel(
    const float* __restrict__ v0W, const float* __restrict__ v1W,
    const float* __restrict__ w0W, const float* __restrict__ w1W,
    const float* __restrict__ pu,  const float* __restrict__ pi,
    u16* __restrict__ Vt0, u16* __restrict__ Vt1,
    u16* __restrict__ Wt0, u16* __restrict__ Wt1,
    u16* __restrict__ Ptu, u16* __restrict__ Pti)
{
    int i = blockIdx.x * 256 + threadIdx.x;
    const float* in; u16* out; int K, idx;
    if      (i <  16384) { in = v0W; out = Vt0; K = 128; idx = i; }
    else if (i <  32768) { in = v1W; out = Vt1; K = 128; idx = i - 16384; }
    else if (i <  65536) { in = w0W; out = Wt0; K = 256; idx = i - 32768; }
    else if (i <  98304) { in = w1W; out = Wt1; K = 256; idx = i - 65536; }
    else if (i < 139264) { in = pu;  out = Ptu; K = 320; idx = i - 98304; }
    else if (i < 180224) { in = pi;  out = Pti; K = 320; idx = i - 139264; }
    else return;
    int k = idx >> 7, n = idx & 127;
    out[(size_t)n * K + k] = f2b(in[idx]);
}

// ---------------- gather tables fp32 -> bf16 (halves gather bytes; one launch) ----------------
__global__ __launch_bounds__(256) void convert_tables_kernel(
    const float* __restrict__ a, int na,
    const float* __restrict__ b, int nb_,
    const float* __restrict__ c, int nc,
    u16* __restrict__ oa, u16* __restrict__ ob, u16* __restrict__ oc)
{
    int total = (na + nb_ + nc) >> 2;
    for (int i = blockIdx.x * 256 + threadIdx.x; i < total; i += gridDim.x * 256) {
        int idx = i << 2;
        const float* src; u16* dst; int off;
        if (idx < na)            { src = a; dst = oa; off = idx; }
        else if (idx < na + nb_) { src = b; dst = ob; off = idx - na; }
        else                     { src = c; dst = oc; off = idx - na - nb_; }
        float4 v = *(const float4*)&src[off];
        ushort4 o;
        o.x = f2b(v.x); o.y = f2b(v.y); o.z = f2b(v.z); o.w = f2b(v.w);
        *(ushort4*)&dst[off] = o;
    }
}

// ---------------- init (user+item merged): bf16-table gather + mean -> LDS, MFMA proj ----------------
__global__ __launch_bounds__(256) void init_mfma_kernel(
    const int* __restrict__ ufeat, const int* __restrict__ utext,
    const u16* __restrict__ ufb,   const u16* __restrict__ uPt,
    const float* __restrict__ upb, const float* __restrict__ uid,
    const int* __restrict__ ifeat, const int* __restrict__ itext,
    const u16* __restrict__ ifb,   const u16* __restrict__ iPt,
    const float* __restrict__ ipb, const float* __restrict__ iid,
    const u16* __restrict__ word_b,   // [30000,64] bf16
    u16* __restrict__ xb,
    int NU, int NI, int ublocks)
{
    __shared__ u16 in_s[INB][328];
    __shared__ int fid_s[INB][10];
    __shared__ int tid_s[INB][24];

    const bool isU = (int)blockIdx.x < ublocks;
    const int* feat_ids = isU ? ufeat : ifeat;
    const int* text_ids = isU ? utext : itext;
    const u16* feat_b   = isU ? ufb   : ifb;
    const u16* Pt       = isU ? uPt   : iPt;
    const float* projb  = isU ? upb   : ipb;
    const float* id_emb = isU ? uid   : iid;
    const int n_nodes   = isU ? NU    : NI;
    const int out_base  = isU ? 0     : NU;
    const int base = (isU ? blockIdx.x : blockIdx.x - ublocks) * INB;
    const int t = threadIdx.x;

    for (int i = t; i < INB * 10; i += 256) {
        int node = i / 10, j = i % 10;
        int g = base + node; if (g > n_nodes - 1) g = n_nodes - 1;
        fid_s[node][j] = feat_ids[(size_t)g * 10 + j];
    }
    for (int i = t; i < INB * 24; i += 256) {
        int node = i / 24, j = i % 24;
        int g = base + node; if (g > n_nodes - 1) g = n_nodes - 1;
        tid_s[node][j] = text_ids[(size_t)g * 24 + j];
    }
    __syncthreads();

    // feat mean: 4 dims/thread, uint2 = 4 bf16 per load
    for (int i = t; i < INB * 32; i += 256) {
        int node = i >> 5, dq = i & 31;
        float a0 = 0.f, a1 = 0.f, a2 = 0.f, a3 = 0.f;
        #pragma unroll
        for (int j = 0; j < 10; ++j) {
            uint2 v = *(const uint2*)&feat_b[(size_t)fid_s[node][j] * D + dq * 4];
            a0 += b2f_lo(v.x); a1 += b2f_hi(v.x);
            a2 += b2f_lo(v.y); a3 += b2f_hi(v.y);
        }
        ushort4 o;
        o.x = f2b(a0 * 0.1f); o.y = f2b(a1 * 0.1f);
        o.z = f2b(a2 * 0.1f); o.w = f2b(a3 * 0.1f);
        *(ushort4*)&in_s[node][dq * 4] = o;
    }
    // text field means: 4 dims/thread
    for (int i = t; i < INB * 48; i += 256) {
        int node = i / 48, r = i % 48;
        int f = r >> 4, dq = r & 15;
        float a0 = 0.f, a1 = 0.f, a2 = 0.f, a3 = 0.f;
        #pragma unroll
        for (int w = 0; w < 8; ++w) {
            uint2 v = *(const uint2*)&word_b[(size_t)tid_s[node][f * 8 + w] * HALF + dq * 4];
            a0 += b2f_lo(v.x); a1 += b2f_hi(v.x);
            a2 += b2f_lo(v.y); a3 += b2f_hi(v.y);
        }
        ushort4 o;
        o.x = f2b(a0 * 0.125f); o.y = f2b(a1 * 0.125f);
        o.z = f2b(a2 * 0.125f); o.w = f2b(a3 * 0.125f);
        *(ushort4*)&in_s[node][128 + f * 64 + dq * 4] = o;
    }
    __syncthreads();

    // ---- out^T = Pt @ in^T (K=320), fused +projb +id_emb, bf16 store ----
    const int wid = t >> 6, lane = t & 63;
    const int row16 = lane & 15, kq = lane >> 4;
    const int g2 = wid >> 1;
    const int oh = wid & 1;
    const int lnode = g2 * 16 + row16;
    const int node = base + lnode;

    short8 Bfrag[10];
    #pragma unroll
    for (int kk = 0; kk < 10; ++kk)
        Bfrag[kk] = *(const short8*)&in_s[lnode][kk * 32 + kq * 8];

    #pragma unroll
    for (int fp = 0; fp < 4; ++fp) {
        const int fn = oh * 4 + fp;
        f32x4 c = {0.f, 0.f, 0.f, 0.f};
        #pragma unroll
        for (int kk = 0; kk < 10; ++kk) {
            short8 A = *(const short8*)&Pt[(size_t)(fn * 16 + row16) * 320 + kk * 32 + kq * 8];
            c = MFMA(A, Bfrag[kk], c, 0, 0, 0);
        }
        if (node < n_nodes) {
            float4 bv = *(const float4*)&projb[fn * 16 + kq * 4];
            float4 ie = *(const float4*)&id_emb[(size_t)node * D + fn * 16 + kq * 4];
            ushort4 ow;
            ow.x = f2b(c[0] + bv.x + ie.x);
            ow.y = f2b(c[1] + bv.y + ie.y);
            ow.z = f2b(c[2] + bv.z + ie.z);
            ow.w = f2b(c[3] + bv.w + ie.w);
            *(ushort4*)&xb[(size_t)(out_base + node) * D + fn * 16 + kq * 4] = ow;
        }
    }
}

// ---------------- CSR build ----------------
__global__ __launch_bounds__(256) void hist_kernel(
    const int* __restrict__ dst, int E, int* __restrict__ deg)
{
    int e = blockIdx.x * 256 + threadIdx.x;
    if (e < E) atomicAdd(&deg[dst[e]], 1);
}

__global__ __launch_bounds__(256) void scan1_kernel(
    const int* __restrict__ deg, int n, int* __restrict__ out_ex, int* __restrict__ bsums)
{
    __shared__ int s[256];
    const int t = threadIdx.x;
    const int base = blockIdx.x * 1024 + t * 4;
    int v0 = 0, v1 = 0, v2 = 0, v3 = 0;
    if (base + 0 < n) v0 = deg[base + 0];
    if (base + 1 < n) v1 = deg[base + 1];
    if (base + 2 < n) v2 = deg[base + 2];
    if (base + 3 < n) v3 = deg[base + 3];
    int sum = v0 + v1 + v2 + v3;
    s[t] = sum;
    __syncthreads();
    for (int off = 1; off < 256; off <<= 1) {
        int tmp = (t >= off) ? s[t - off] : 0;
        __syncthreads();
        s[t] += tmp;
        __syncthreads();
    }
    int ex = s[t] - sum;
    if (t == 255) bsums[blockIdx.x] = s[255];
    if (base + 0 < n) out_ex[base + 0] = ex;
    if (base + 1 < n) out_ex[base + 1] = ex + v0;
    if (base + 2 < n) out_ex[base + 2] = ex + v0 + v1;
    if (base + 3 < n) out_ex[base + 3] = ex + v0 + v1 + v2;
}

__global__ __launch_bounds__(256) void scan2_kernel(int* __restrict__ bsums, int nb)
{
    __shared__ int s[256];
    const int t = threadIdx.x;
    int v = (t < nb) ? bsums[t] : 0;
    s[t] = v;
    __syncthreads();
    for (int off = 1; off < 256; off <<= 1) {
        int tmp = (t >= off) ? s[t - off] : 0;
        __syncthreads();
        s[t] += tmp;
        __syncthreads();
    }
    if (t < nb) bsums[t] = s[t] - v;
}

__global__ __launch_bounds__(256) void scan3_kernel(
    int* __restrict__ row_ptr, const int* __restrict__ bsums, int n, int E)
{
    const int add = bsums[blockIdx.x];
    const int base = blockIdx.x * 1024 + threadIdx.x * 4;
    #pragma unroll
    for (int j = 0; j < 4; ++j)
        if (base + j < n) row_ptr[base + j] += add;
    if (blockIdx.x == 0 && threadIdx.x == 0) row_ptr[n] = E;
}

__global__ __launch_bounds__(256) void fill_kernel(
    const int* __restrict__ src, const int* __restrict__ dst, int E,
    const int* __restrict__ row_ptr, int* __restrict__ cursor, int* __restrict__ ebuf)
{
    int e = blockIdx.x * 256 + threadIdx.x;
    if (e < E) {
        int d = dst[e];
        int slot = atomicAdd(&cursor[d], 1);
        ebuf[row_ptr[d] + slot] = src[e];
    }
}

// ---------------- gather aggregate (bf16), 4-way ILP unroll ----------------
__global__ __launch_bounds__(256) void aggregate_kernel(
    const int* __restrict__ row_ptr, const int* __restrict__ ebuf,
    const u16* __restrict__ xb, u16* __restrict__ aggm, int n_nodes)
{
    const int wave = threadIdx.x >> 6;
    const int lane = threadIdx.x & 63;
    const int g = blockIdx.x * 4 + wave;
    if (g >= n_nodes) return;
    const int s0 = row_ptr[g], s1 = row_ptr[g + 1];
    float ax = 0.f, ay = 0.f, bx = 0.f, by = 0.f;
    int e = s0;
    for (; e + 4 <= s1; e += 4) {
        int n0 = ebuf[e], n1 = ebuf[e + 1], n2 = ebuf[e + 2], n3 = ebuf[e + 3];
        u32 v0 = *(const u32*)&xb[(size_t)n0 * D + lane * 2];
        u32 v1 = *(const u32*)&xb[(size_t)n1 * D + lane * 2];
        u32 v2 = *(const u32*)&xb[(size_t)n2 * D + lane * 2];
        u32 v3 = *(const u32*)&xb[(size_t)n3 * D + lane * 2];
        ax += b2f_lo(v0) + b2f_lo(v1);
        ay += b2f_hi(v0) + b2f_hi(v1);
        bx += b2f_lo(v2) + b2f_lo(v3);
        by += b2f_hi(v2) + b2f_hi(v3);
    }
    for (; e < s1; ++e) {
        u32 v = *(const u32*)&xb[(size_t)ebuf[e] * D + lane * 2];
        ax += b2f_lo(v);
        ay += b2f_hi(v);
    }
    ax += bx; ay += by;
    const float inv = 1.0f / fmaxf((float)(s1 - s0), 1.0f);
    u32 o = (u32)f2b(ax * inv) | ((u32)f2b(ay * inv) << 16);
    *(u32*)&aggm[(size_t)g * D + lane * 2] = o;
}

// ---------------- SAGE layer via MFMA, fn-split across 8 waves (R8 race-fix kept) ----------------
__global__ __launch_bounds__(512, 4) void sage_mfma_kernel(
    const u16* __restrict__ xb, const u16* __restrict__ aggm,
    const u16* __restrict__ Vt,  const float* __restrict__ vb,   // Vt [128][128]
    const u16* __restrict__ Wt,  const float* __restrict__ wb,   // Wt [128][256]
    u16* __restrict__ xb_out,    // layer0: write bf16 in place (else null)
    float* __restrict__ f_out,   // layer1: write fp32 d_out (else null)
    int n_nodes)
{
    __shared__ u16 t_lds[32][136];
    const int wid  = threadIdx.x >> 6;   // 0..7 = fn
    const int lane = threadIdx.x & 63;
    const int row16 = lane & 15;
    const int kq    = lane >> 4;
    const int nb = blockIdx.x * 32;

    const int node0 = nb + row16;
    const int node1 = nb + 16 + row16;
    const int ncl0 = node0 < n_nodes ? node0 : n_nodes - 1;
    const int ncl1 = node1 < n_nodes ? node1 : n_nodes - 1;

    short8 Av[4];
    #pragma unroll
    for (int kk = 0; kk < 4; ++kk)
        Av[kk] = *(const short8*)&Vt[(size_t)(wid * 16 + row16) * 128 + kk * 32 + kq * 8];

    #pragma unroll
    for (int g = 0; g < 2; ++g) {
        const int nclamp = g ? ncl1 : ncl0;
        f32x4 c = {0.f, 0.f, 0.f, 0.f};
        #pragma unroll
        for (int kk = 0; kk < 4; ++kk) {
            short8 B = *(const short8*)&aggm[(size_t)nclamp * D + kk * 32 + kq * 8];
            c = MFMA(Av[kk], B, c, 0, 0, 0);
        }
        float4 bv = *(const float4*)&vb[wid * 16 + kq * 4];
        ushort4 tw;
        tw.x = f2b(fmaxf(c[0] + bv.x, 0.f));
        tw.y = f2b(fmaxf(c[1] + bv.y, 0.f));
        tw.z = f2b(fmaxf(c[2] + bv.z, 0.f));
        tw.w = f2b(fmaxf(c[3] + bv.w, 0.f));
        *(ushort4*)&t_lds[g * 16 + row16][wid * 16 + kq * 4] = tw;
    }

    short8 Aw[8];
    #pragma unroll
    for (int kk = 0; kk < 8; ++kk)
        Aw[kk] = *(const short8*)&Wt[(size_t)(wid * 16 + row16) * 256 + kk * 32 + kq * 8];

    short8 Bx0[4], Bx1[4];
    #pragma unroll
    for (int kk = 0; kk < 4; ++kk)
        Bx0[kk] = *(const short8*)&xb[(size_t)ncl0 * D + kk * 32 + kq * 8];
    #pragma unroll
    for (int kk = 0; kk < 4; ++kk)
        Bx1[kk] = *(const short8*)&xb[(size_t)ncl1 * D + kk * 32 + kq * 8];

    __syncthreads();   // t_lds ready; all xb reads complete; writes may begin

    #pragma unroll
    for (int g = 0; g < 2; ++g) {
        const int node = g ? node1 : node0;
        f32x4 c = {0.f, 0.f, 0.f, 0.f};
        #pragma unroll
        for (int kk = 0; kk < 4; ++kk)
            c = MFMA(Aw[kk], g ? Bx1[kk] : Bx0[kk], c, 0, 0, 0);
        #pragma unroll
        for (int kk = 0; kk < 4; ++kk) {
            short8 B = *(const short8*)&t_lds[g * 16 + row16][kk * 32 + kq * 8];
            c = MFMA(Aw[4 + kk], B, c, 0, 0, 0);
        }
        if (node < n_nodes) {
            float4 bv = *(const float4*)&wb[wid * 16 + kq * 4];
            float o0 = c[0] + bv.x, o1 = c[1] + bv.y, o2 = c[2] + bv.z, o3 = c[3] + bv.w;
            if (xb_out) {
                ushort4 ow;
                ow.x = f2b(fmaxf(o0, 0.f));
                ow.y = f2b(fmaxf(o1, 0.f));
                ow.z = f2b(fmaxf(o2, 0.f));
                ow.w = f2b(fmaxf(o3, 0.f));
                *(ushort4*)&xb_out[(size_t)node * D + wid * 16 + kq * 4] = ow;
            } else {
                float4 ow = make_float4(o0, o1, o2, o3);
                *(float4*)&f_out[(size_t)node * D + wid * 16 + kq * 4] = ow;
            }
        }
    }
}

extern "C" void kernel_launch(void* const* d_in, const int* in_sizes, int n_in,
                              void* d_out, int out_size, void* d_ws, size_t ws_size,
                              hipStream_t stream)
{
    const int* edge_index      = (const int*)d_in[0];
    const int* user_features   = (const int*)d_in[1];
    const int* item_features   = (const int*)d_in[2];
    const int* user_text       = (const int*)d_in[3];
    const int* item_text       = (const int*)d_in[4];
    const float* user_id_emb   = (const float*)d_in[5];
    const float* item_id_emb   = (const float*)d_in[6];
    const float* user_feat_emb = (const float*)d_in[7];
    const float* item_feat_emb = (const float*)d_in[8];
    const float* word_emb      = (const float*)d_in[9];
    const float* user_projW    = (const float*)d_in[10];
    const float* user_projb    = (const float*)d_in[11];
    const float* item_projW    = (const float*)d_in[12];
    const float* item_projb    = (const float*)d_in[13];
    const float* w0W = (const float*)d_in[14];
    const float* w0b = (const float*)d_in[15];
    const float* w1W = (const float*)d_in[16];
    const float* w1b = (const float*)d_in[17];
    const float* v0W = (const float*)d_in[18];
    const float* v0b = (const float*)d_in[19];
    const float* v1W = (const float*)d_in[20];
    const float* v1b = (const float*)d_in[21];

    const int E  = in_sizes[0] / 2;
    const int NU = in_sizes[5] / D;
    const int NI = in_sizes[6] / D;
    const int N  = NU + NI;
    const int NB = (N + 1023) / 1024;
    const int nFU = in_sizes[7];     // user_feat_emb elems (5000*128)
    const int nFI = in_sizes[8];     // item_feat_emb elems (8000*128)
    const int nW  = in_sizes[9];     // word_emb elems (30000*64)

    // workspace layout
    u16* xb   = (u16*)d_ws;                       // [N,128] bf16
    u16* aggm = xb + (size_t)N * D;               // [N,128] bf16
    u16* Vt0  = aggm + (size_t)N * D;             // [128,128]
    u16* Vt1  = Vt0 + 128 * 128;
    u16* Wt0  = Vt1 + 128 * 128;                  // [128,256]
    u16* Wt1  = Wt0 + 256 * 128;
    u16* Pt_u = Wt1 + 256 * 128;                  // [128,320]
    u16* Pt_i = Pt_u + 128 * 320;                 // [128,320]
    u16* fb_u = Pt_i + 128 * 320;                 // [5000,128] bf16
    u16* fb_i = fb_u + (size_t)nFU;               // [8000,128] bf16
    u16* wd_b = fb_i + (size_t)nFI;               // [30000,64] bf16
    int* row_ptr = (int*)(wd_b + (size_t)nW);     // [N+1]
    int* deg_i   = row_ptr + (N + 1);             // [N]
    int* cursor  = deg_i + N;                     // [N]
    int* bsums   = cursor + N;                    // [256]
    int* ebuf    = bsums + 256;                   // [E]

    hipMemsetAsync(deg_i, 0, (size_t)(2 * N) * sizeof(int), stream);

    const int* src = edge_index;
    const int* dst = edge_index + E;
    dim3 blk(256);

    // weight transposes (1 launch) + table conversions (1 launch)
    transpose_all_kernel<<<(180224 + 255) / 256, blk, 0, stream>>>(
        v0W, v1W, w0W, w1W, user_projW, item_projW,
        Vt0, Vt1, Wt0, Wt1, Pt_u, Pt_i);
    convert_tables_kernel<<<2048, blk, 0, stream>>>(
        user_feat_emb, nFU, item_feat_emb, nFI, word_emb, nW,
        fb_u, fb_i, wd_b);

    // init: user+item in one grid
    const int ublocks = (NU + INB - 1) / INB;
    const int iblocks = (NI + INB - 1) / INB;
    init_mfma_kernel<<<ublocks + iblocks, blk, 0, stream>>>(
        user_features, user_text, fb_u, Pt_u, user_projb, user_id_emb,
        item_features, item_text, fb_i, Pt_i, item_projb, item_id_emb,
        wd_b, xb, NU, NI, ublocks);

    // CSR build
    hist_kernel<<<(E + 255) / 256, blk, 0, stream>>>(dst, E, deg_i);
    scan1_kernel<<<NB, blk, 0, stream>>>(deg_i, N, row_ptr, bsums);
    scan2_kernel<<<1, blk, 0, stream>>>(bsums, NB);
    scan3_kernel<<<NB, blk, 0, stream>>>(row_ptr, bsums, N, E);
    fill_kernel<<<(E + 255) / 256, blk, 0, stream>>>(src, dst, E, row_ptr, cursor, ebuf);

    const int sage_grid = (N + 31) / 32;
    dim3 sblk(512);

    // layer 0 (relu, bf16 in-place)
    aggregate_kernel<<<(N + 3) / 4, blk, 0, stream>>>(row_ptr, ebuf, xb, aggm, N);
    sage_mfma_kernel<<<sage_grid, sblk, 0, stream>>>(
        xb, aggm, Vt0, v0b, Wt0, w0b, xb, nullptr, N);

    // layer 1 (no relu, fp32 -> d_out)
    aggregate_kernel<<<(N + 3) / 4, blk, 0, stream>>>(row_ptr, ebuf, xb, aggm, N);
    sage_mfma_kernel<<<sage_grid, sblk, 0, stream>>>(
        xb, aggm, Vt1, v1b, Wt1, w1b, nullptr, (float*)d_out, N);
}